// Round 1
// 1065.673 us; speedup vs baseline: 1.2687x; 1.2687x over previous
//
#include <hip/hip_runtime.h>
#include <hip/hip_bf16.h>
#include <math.h>

typedef __hip_bfloat16 bf16;
typedef __attribute__((ext_vector_type(8))) short short8;
typedef __attribute__((ext_vector_type(4))) float f32x4;

#define Bb 64
#define Hh 56
#define Ww 56
#define Cc 128
#define WS 7
#define SHIFT 3
#define NH 4
#define HD 32
#define Nn 49
#define NW 64
#define HID 512

// ws layout (shorts): qkv_w @0 (49152), proj_w @49152 (16384), fc1_w @65536 (65536), fc2_w @131072 (65536)
// biasT (float) @ byte 393216: [4][49][49]
#define WS_QKV 0
#define WS_PROJ 49152
#define WS_FC1 65536
#define WS_FC2 131072
#define WS_BIAS_BYTES 393216

__device__ __forceinline__ short fb(float v) { return __builtin_bit_cast(short, __float2bfloat16(v)); }

// ---------------- prep: weights fp32->bf16 into ws; gather rel-bias table ----------------
__global__ __launch_bounds__(256) void prep_kernel(
    const float* __restrict__ qkv_w, const float* __restrict__ proj_w,
    const float* __restrict__ fc1_w, const float* __restrict__ fc2_w,
    const float* __restrict__ rel_bias, const int* __restrict__ rel_index,
    short* __restrict__ wsb, float* __restrict__ biasT)
{
    int t = blockIdx.x * 256 + threadIdx.x;
    if (t < 49152)       wsb[t] = fb(qkv_w[t]);
    else if (t < 65536)  wsb[t] = fb(proj_w[t - 49152]);
    else if (t < 131072) wsb[t] = fb(fc1_w[t - 65536]);
    else if (t < 196608) wsb[t] = fb(fc2_w[t - 131072]);
    if (t < 4 * Nn * Nn) {
        int h = t / (Nn * Nn), r = t - h * (Nn * Nn);
        biasT[t] = rel_bias[rel_index[r] * NH + h];
    }
}

// ---------------- attention: one block per window, 8 waves (512 thr) ----------------
// LDS strides (elements, all %8==0 for 16B ds_read alignment, ~2-way banks):
#define SW 136   // win/ao row stride (128 cols)
#define SQ 40    // qs/ks row stride (32 cols)
#define SV 72    // vT row stride (64 cols)
#define SP 72    // p row stride (64 cols)

// LDS budget: win 17408 B + qk (qs+ks) 40960 B + vT 18432 B = 76800 B -> 2 blocks/CU.
// pm (4*64*SP = 36864 B) ALIASES qk: q/k fragments are register-preloaded before a
// barrier, after which qs/ks are dead and pm reuses the space.
__global__ __launch_bounds__(512, 4) void attn_kernel(
    const float* __restrict__ x,          // (B,3136,128) shortcut
    const float* __restrict__ x_norm1,    // (B,3136,128)
    const float* __restrict__ qkv_b,      // (384)
    const float* __restrict__ proj_b,     // (128)
    const float* __restrict__ attn_mask,  // (64,49,49)
    const short* __restrict__ wsb,        // bf16 weights
    const float* __restrict__ biasT,      // (4,49,49)
    float* __restrict__ out)
{
    __shared__ short win[64 * SW];            // window tile; reused as attn_out
    __shared__ short qk[2 * NH * 64 * SQ];    // qs @0, ks @ NH*64*SQ; pm aliases @0
    __shared__ short vT[NH * HD * SV];

    const int blk = blockIdx.x;
    const int b   = blk >> 6;
    const int nw  = blk & 63;
    const int wh  = nw >> 3;
    const int wwi = nw & 7;
    const int tid  = threadIdx.x;
    const int wave = tid >> 6;
    const int lane = tid & 63;
    const int quad = lane >> 4;
    const int l16  = lane & 15;
    const int wm   = wave & 3;     // m-tile / head index
    const int half = wave >> 2;    // 0/1: n-tile split within phase

    const int KS_OFF = NH * 64 * SQ;   // ks base inside qk

    // ---- gather shifted window (rows 49..63 zero) ----
    for (int idx = tid; idx < 64 * Cc; idx += 512) {
        int t = idx >> 7, c = idx & 127;
        float v = 0.f;
        if (t < Nn) {
            int i = t / WS, j = t - i * WS;
            int hh = wh * WS + i + SHIFT; if (hh >= Hh) hh -= Hh;
            int wp = wwi * WS + j + SHIFT; if (wp >= Ww) wp -= Ww;
            v = x_norm1[((size_t)b * (Hh * Ww) + hh * Ww + wp) * Cc + c];
        }
        win[t * SW + c] = fb(v);
    }
    __syncthreads();

    // ---- QKV: wave (wm,half): m-tile wm, n-tiles [half*12, half*12+12), K=128 ----
    {
        short8 a1[4];
        #pragma unroll
        for (int kk = 0; kk < 4; ++kk)
            a1[kk] = *(const short8*)&win[(wm * 16 + l16) * SW + kk * 32 + quad * 8];
        const short* wq = wsb + WS_QKV;
        for (int nt = half * 12; nt < half * 12 + 12; ++nt) {
            f32x4 c = {0.f, 0.f, 0.f, 0.f};
            int n = nt * 16 + l16;
            #pragma unroll
            for (int kk = 0; kk < 4; ++kk) {
                short8 bf = *(const short8*)&wq[n * Cc + kk * 32 + quad * 8];
                c = __builtin_amdgcn_mfma_f32_16x16x32_bf16(a1[kk], bf, c, 0, 0, 0);
            }
            int oc = n;
            int g = oc >> 7, ch = oc & 127, head = ch >> 5, d = ch & 31;
            float bias = qkv_b[oc];
            #pragma unroll
            for (int r = 0; r < 4; ++r) {
                int tok = wm * 16 + quad * 4 + r;
                float val = c[r] + bias;
                if (g == 0)      qk[head * 64 * SQ + tok * SQ + d] = fb(val * 0.17677669529663689f);
                else if (g == 1) qk[KS_OFF + head * 64 * SQ + tok * SQ + d] = fb(val);
                else             vT[head * HD * SV + d * SV + tok] = fb(val);
            }
        }
    }
    __syncthreads();

    // ---- preload q/k fragments to registers, then free qs/ks for pm ----
    const int head = wm;
    short8 bk[4], aq[2];
    #pragma unroll
    for (int nt = 0; nt < 4; ++nt)
        bk[nt] = *(const short8*)&qk[KS_OFF + head * 64 * SQ + (nt * 16 + l16) * SQ + quad * 8];
    #pragma unroll
    for (int i = 0; i < 2; ++i)
        aq[i] = *(const short8*)&qk[head * 64 * SQ + ((half * 2 + i) * 16 + l16) * SQ + quad * 8];
    __syncthreads();   // all q/k now in regs; pm may overwrite qk

    // ---- scores + softmax: wave (head,half) handles m-tiles {2*half, 2*half+1} ----
    {
        const float* bT = biasT + head * (Nn * Nn);
        const float* mk = attn_mask + nw * (Nn * Nn);
        #pragma unroll
        for (int i = 0; i < 2; ++i) {
            int mt = half * 2 + i;
            f32x4 sc[4];
            #pragma unroll
            for (int nt = 0; nt < 4; ++nt) {
                f32x4 z = {0.f, 0.f, 0.f, 0.f};
                sc[nt] = __builtin_amdgcn_mfma_f32_16x16x32_bf16(aq[i], bk[nt], z, 0, 0, 0);
            }
            #pragma unroll
            for (int r = 0; r < 4; ++r) {
                int row = mt * 16 + quad * 4 + r;
                bool rowv = row < Nn;
                float v[4];
                #pragma unroll
                for (int nt = 0; nt < 4; ++nt) {
                    int col = nt * 16 + l16;
                    float s = sc[nt][r];
                    if (rowv && col < Nn) s += bT[row * Nn + col] + mk[row * Nn + col];
                    else s = -1e30f;
                    v[nt] = s;
                }
                float mx = fmaxf(fmaxf(v[0], v[1]), fmaxf(v[2], v[3]));
                #pragma unroll
                for (int off = 1; off < 16; off <<= 1) mx = fmaxf(mx, __shfl_xor(mx, off, 64));
                float e[4]; float sum = 0.f;
                #pragma unroll
                for (int nt = 0; nt < 4; ++nt) { e[nt] = __expf(v[nt] - mx); sum += e[nt]; }
                #pragma unroll
                for (int off = 1; off < 16; off <<= 1) sum += __shfl_xor(sum, off, 64);
                float inv = 1.f / sum;
                #pragma unroll
                for (int nt = 0; nt < 4; ++nt)
                    qk[head * 64 * SP + row * SP + nt * 16 + l16] = fb(e[nt] * inv);  // pm alias
            }
        }
    }
    // pm rows for this wave's m-tiles are wave-private; vT stable since QKV barrier.

    // ---- PV: O rows [half*32, half*32+32) x 32 per (head,half) ----
    {
        f32x4 o[2][2];
        #pragma unroll
        for (int i = 0; i < 2; ++i)
            #pragma unroll
            for (int nt = 0; nt < 2; ++nt) o[i][nt] = f32x4{0.f, 0.f, 0.f, 0.f};
        #pragma unroll
        for (int kstep = 0; kstep < 2; ++kstep) {
            short8 bv[2];
            #pragma unroll
            for (int nt = 0; nt < 2; ++nt)
                bv[nt] = *(const short8*)&vT[head * HD * SV + (nt * 16 + l16) * SV + kstep * 32 + quad * 8];
            #pragma unroll
            for (int i = 0; i < 2; ++i) {
                short8 ap = *(const short8*)&qk[head * 64 * SP + ((half * 2 + i) * 16 + l16) * SP + kstep * 32 + quad * 8];
                #pragma unroll
                for (int nt = 0; nt < 2; ++nt)
                    o[i][nt] = __builtin_amdgcn_mfma_f32_16x16x32_bf16(ap, bv[nt], o[i][nt], 0, 0, 0);
            }
        }
        // write attn_out into win (all win reads finished before the post-QKV barrier)
        #pragma unroll
        for (int i = 0; i < 2; ++i)
            #pragma unroll
            for (int nt = 0; nt < 2; ++nt)
                #pragma unroll
                for (int r = 0; r < 4; ++r) {
                    int tok = (half * 2 + i) * 16 + quad * 4 + r;
                    int cch = head * HD + nt * 16 + l16;
                    win[tok * SW + cch] = fb(o[i][nt][r]);
                }
    }
    __syncthreads();

    // ---- proj + residual + scatter: wave (wm,half): m-tile wm, n-tiles [half*4, half*4+4) ----
    {
        short8 a[4];
        #pragma unroll
        for (int kk = 0; kk < 4; ++kk)
            a[kk] = *(const short8*)&win[(wm * 16 + l16) * SW + kk * 32 + quad * 8];
        const short* wp_ = wsb + WS_PROJ;
        for (int nt2 = half * 4; nt2 < half * 4 + 4; ++nt2) {
            int n = nt2 * 16 + l16;
            f32x4 c = {0.f, 0.f, 0.f, 0.f};
            #pragma unroll
            for (int kk = 0; kk < 4; ++kk) {
                short8 bf = *(const short8*)&wp_[n * Cc + kk * 32 + quad * 8];
                c = __builtin_amdgcn_mfma_f32_16x16x32_bf16(a[kk], bf, c, 0, 0, 0);
            }
            float pb = proj_b[n];
            #pragma unroll
            for (int r = 0; r < 4; ++r) {
                int tok = wm * 16 + quad * 4 + r;
                if (tok < Nn) {
                    int i = tok / WS, j = tok - i * WS;
                    int hh = wh * WS + i + SHIFT; if (hh >= Hh) hh -= Hh;
                    int wpp = wwi * WS + j + SHIFT; if (wpp >= Ww) wpp -= Ww;
                    size_t addr = ((size_t)b * (Hh * Ww) + hh * Ww + wpp) * Cc + n;
                    out[addr] = x[addr] + c[r] + pb;
                }
            }
        }
    }
}

// ---------------- MLP: 64 tokens/block, LN -> fc1 -> GELU -> fc2 -> residual ----------------
#define SH 136   // hb row stride
#define SG 40    // g tile row stride

__global__ __launch_bounds__(256) void mlp_kernel(
    const float* __restrict__ norm2_w, const float* __restrict__ norm2_b,
    const float* __restrict__ fc1_b,   const float* __restrict__ fc2_b,
    const short* __restrict__ wsb,
    float* __restrict__ xio)
{
    __shared__ short hb[64 * SH];
    __shared__ short gt[NH][16 * SG];
    __shared__ float b1[HID], b2[Cc];

    const int tid  = threadIdx.x;
    const int wave = tid >> 6;
    const int lane = tid & 63;
    const int quad = lane >> 4;
    const int l16  = lane & 15;
    const size_t base = (size_t)blockIdx.x * 64 * Cc;

    for (int i = tid; i < HID; i += 256) b1[i] = fc1_b[i];
    if (tid < Cc) b2[tid] = fc2_b[tid];

    // ---- LN: 4 threads per token ----
    {
        int t = tid >> 2, qtr = tid & 3;
        const float* xr = xio + base + t * Cc + qtr * 32;
        float vals[32];
        float s1 = 0.f, s2 = 0.f;
        #pragma unroll
        for (int k8 = 0; k8 < 8; ++k8) {
            f32x4 v4 = *(const f32x4*)&xr[k8 * 4];
            #pragma unroll
            for (int u = 0; u < 4; ++u) {
                float v = v4[u];
                vals[k8 * 4 + u] = v;
                s1 += v; s2 += v * v;
            }
        }
        s1 += __shfl_xor(s1, 1, 64); s1 += __shfl_xor(s1, 2, 64);
        s2 += __shfl_xor(s2, 1, 64); s2 += __shfl_xor(s2, 2, 64);
        float mu = s1 * (1.f / Cc);
        float var = s2 * (1.f / Cc) - mu * mu;
        float rs = rsqrtf(var + 1e-5f);
        #pragma unroll
        for (int k = 0; k < 32; ++k) {
            int c = qtr * 32 + k;
            hb[t * SH + c] = fb((vals[k] - mu) * rs * norm2_w[c] + norm2_b[c]);
        }
    }
    __syncthreads();

    // ---- fc1 -> GELU -> fc2 (chunked over hidden) ----
    {
        short8 a1[4];
        #pragma unroll
        for (int kk = 0; kk < 4; ++kk)
            a1[kk] = *(const short8*)&hb[(wave * 16 + l16) * SH + kk * 32 + quad * 8];
        const short* w1 = wsb + WS_FC1;
        const short* w2 = wsb + WS_FC2;
        f32x4 acc[8];
        #pragma unroll
        for (int n2 = 0; n2 < 8; ++n2) acc[n2] = f32x4{0.f, 0.f, 0.f, 0.f};

        for (int h = 0; h < 16; ++h) {
            #pragma unroll
            for (int nt = 0; nt < 2; ++nt) {
                int n = h * 32 + nt * 16 + l16;
                f32x4 c = {0.f, 0.f, 0.f, 0.f};
                #pragma unroll
                for (int kk = 0; kk < 4; ++kk) {
                    short8 bf = *(const short8*)&w1[n * Cc + kk * 32 + quad * 8];
                    c = __builtin_amdgcn_mfma_f32_16x16x32_bf16(a1[kk], bf, c, 0, 0, 0);
                }
                float bb = b1[n];
                #pragma unroll
                for (int r = 0; r < 4; ++r) {
                    float v = c[r] + bb;
                    float g = 0.5f * v * (1.f + erff(v * 0.70710678118654752f));
                    gt[wave][(quad * 4 + r) * SG + nt * 16 + l16] = fb(g);
                }
            }
            // wave-private tile: lockstep write->read, no block barrier needed
            short8 a2 = *(const short8*)&gt[wave][l16 * SG + quad * 8];
            #pragma unroll
            for (int n2 = 0; n2 < 8; ++n2) {
                short8 bf = *(const short8*)&w2[(n2 * 16 + l16) * HID + h * 32 + quad * 8];
                acc[n2] = __builtin_amdgcn_mfma_f32_16x16x32_bf16(a2, bf, acc[n2], 0, 0, 0);
            }
        }
        // epilogue: + bias + residual, in place
        #pragma unroll
        for (int n2 = 0; n2 < 8; ++n2) {
            int cch = n2 * 16 + l16;
            float bb = b2[cch];
            #pragma unroll
            for (int r = 0; r < 4; ++r) {
                int tok = wave * 16 + quad * 4 + r;
                size_t ad = base + (size_t)tok * Cc + cch;
                xio[ad] = xio[ad] + acc[n2][r] + bb;
            }
        }
    }
}

extern "C" void kernel_launch(void* const* d_in, const int* in_sizes, int n_in,
                              void* d_out, int out_size, void* d_ws, size_t ws_size,
                              hipStream_t stream) {
    const float* x         = (const float*)d_in[0];
    const float* x_norm1   = (const float*)d_in[1];
    const float* qkv_w     = (const float*)d_in[2];
    const float* qkv_b     = (const float*)d_in[3];
    const float* rel_bias  = (const float*)d_in[4];
    const float* proj_w    = (const float*)d_in[5];
    const float* proj_b    = (const float*)d_in[6];
    const float* norm2_w   = (const float*)d_in[7];
    const float* norm2_b   = (const float*)d_in[8];
    const float* fc1_w     = (const float*)d_in[9];
    const float* fc1_b     = (const float*)d_in[10];
    const float* fc2_w     = (const float*)d_in[11];
    const float* fc2_b     = (const float*)d_in[12];
    const float* attn_mask = (const float*)d_in[13];
    const int*   rel_index = (const int*)d_in[14];
    float* out = (float*)d_out;

    short* wsb   = (short*)d_ws;
    float* biasT = (float*)((char*)d_ws + WS_BIAS_BYTES);

    prep_kernel<<<768, 256, 0, stream>>>(qkv_w, proj_w, fc1_w, fc2_w,
                                         rel_bias, rel_index, wsb, biasT);

    attn_kernel<<<Bb * NW, 512, 0, stream>>>(x, x_norm1, qkv_b, proj_b,
                                             attn_mask, wsb, biasT, out);

    mlp_kernel<<<Bb * Hh * Ww / 64, 256, 0, stream>>>(norm2_w, norm2_b, fc1_b,
                                                      fc2_b, wsb, out);
}

// Round 3
// 747.342 us; speedup vs baseline: 1.8090x; 1.4260x over previous
//
#include <hip/hip_runtime.h>
#include <hip/hip_bf16.h>
#include <math.h>

typedef __hip_bfloat16 bf16;
typedef __attribute__((ext_vector_type(8))) short short8;
typedef __attribute__((ext_vector_type(4))) short s4v;
typedef __attribute__((ext_vector_type(4))) float f32x4;

#define Bb 64
#define Hh 56
#define Ww 56
#define Cc 128
#define WS 7
#define SHIFT 3
#define NH 4
#define HD 32
#define Nn 49
#define NW 64
#define HID 512

// ws layout (shorts): qkv_w @0 (49152), proj_w @49152 (16384), fc1_w @65536 (65536), fc2_w @131072 (65536)
// biasT (float) @ byte 393216: [4][49][49]
#define WS_QKV 0
#define WS_PROJ 49152
#define WS_FC1 65536
#define WS_FC2 131072
#define WS_BIAS_BYTES 393216

__device__ __forceinline__ short fb(float v) { return __builtin_bit_cast(short, __float2bfloat16(v)); }

// exp-based tanh GELU: |err| vs exact erf-GELU < 1e-3 absolute (safe vs 0.031 absmax budget).
// t = 1 - 2/(e^{2y}+1) is overflow-safe: e=inf -> t=1, e=0 -> t=-1.
__device__ __forceinline__ float fgelu(float x) {
    float y = 0.7978845608028654f * (x + 0.044715f * x * x * x);
    float e = __expf(2.f * y);
    float t = 1.f - 2.f / (e + 1.f);
    return 0.5f * x * (1.f + t);
}

// ---------------- prep: weights fp32->bf16 into ws; gather rel-bias table ----------------
__global__ __launch_bounds__(256) void prep_kernel(
    const float* __restrict__ qkv_w, const float* __restrict__ proj_w,
    const float* __restrict__ fc1_w, const float* __restrict__ fc2_w,
    const float* __restrict__ rel_bias, const int* __restrict__ rel_index,
    short* __restrict__ wsb, float* __restrict__ biasT)
{
    int t = blockIdx.x * 256 + threadIdx.x;
    if (t < 49152)       wsb[t] = fb(qkv_w[t]);
    else if (t < 65536)  wsb[t] = fb(proj_w[t - 49152]);
    else if (t < 131072) wsb[t] = fb(fc1_w[t - 65536]);
    else if (t < 196608) wsb[t] = fb(fc2_w[t - 131072]);
    if (t < 4 * Nn * Nn) {
        int h = t / (Nn * Nn), r = t - h * (Nn * Nn);
        biasT[t] = rel_bias[rel_index[r] * NH + h];
    }
}

// ---------------- attention: one block per window, 8 waves (512 thr) ----------------
// LDS strides (elements, all %8==0 for 16B ds_read alignment, ~2-way banks):
#define SW 136   // win/ao row stride (128 cols)
#define SQ 40    // qs/ks row stride (32 cols)
#define SV 72    // vT row stride (64 cols)
#define SP 72    // p row stride (64 cols)

// LDS budget: win 17408 B + qk (qs+ks) 40960 B + vT 18432 B = 76800 B -> 2 blocks/CU.
// pm (4*64*SP = 36864 B) ALIASES qk: q/k fragments are register-preloaded before a
// barrier, after which qs/ks are dead and pm reuses the space.
__global__ __launch_bounds__(512, 4) void attn_kernel(
    const float* __restrict__ x,          // (B,3136,128) shortcut
    const float* __restrict__ x_norm1,    // (B,3136,128)
    const float* __restrict__ qkv_b,      // (384)
    const float* __restrict__ proj_b,     // (128)
    const float* __restrict__ attn_mask,  // (64,49,49)
    const short* __restrict__ wsb,        // bf16 weights
    const float* __restrict__ biasT,      // (4,49,49)
    float* __restrict__ out)
{
    __shared__ short win[64 * SW];            // window tile; reused as attn_out
    __shared__ short qk[2 * NH * 64 * SQ];    // qs @0, ks @ NH*64*SQ; pm aliases @0
    __shared__ short vT[NH * HD * SV];

    const int blk = blockIdx.x;
    const int b   = blk >> 6;
    const int nw  = blk & 63;
    const int wh  = nw >> 3;
    const int wwi = nw & 7;
    const int tid  = threadIdx.x;
    const int wave = tid >> 6;
    const int lane = tid & 63;
    const int quad = lane >> 4;
    const int l16  = lane & 15;
    const int half = wave >> 2;    // 0/1 split used by score/PV phases
    const int mp   = wave >> 2;    // m-pair for QKV/proj phases
    const int wq   = wave & 3;     // n-quarter for QKV/proj phases

    const int KS_OFF = NH * 64 * SQ;   // ks base inside qk

    // ---- gather shifted window, float4-vectorized (rows 49..63 zero) ----
    for (int idx = tid; idx < 64 * 32; idx += 512) {
        int t = idx >> 5, c4 = (idx & 31) * 4;
        f32x4 v = {0.f, 0.f, 0.f, 0.f};
        if (t < Nn) {
            int i = t / WS, j = t - i * WS;
            int hh = wh * WS + i + SHIFT; if (hh >= Hh) hh -= Hh;
            int wp = wwi * WS + j + SHIFT; if (wp >= Ww) wp -= Ww;
            v = *(const f32x4*)&x_norm1[((size_t)b * (Hh * Ww) + hh * Ww + wp) * Cc + c4];
        }
        s4v sv;
        #pragma unroll
        for (int u = 0; u < 4; ++u) sv[u] = fb(v[u]);
        *(s4v*)&win[t * SW + c4] = sv;
    }
    __syncthreads();

    // ---- QKV: wave (wq,mp): m-tiles {2mp,2mp+1}, n-tiles [wq*6, wq*6+6) ----
    // Each weight fragment feeds 2 MFMA (both m-tiles).
    {
        short8 a1[2][4];
        #pragma unroll
        for (int mt = 0; mt < 2; ++mt)
            #pragma unroll
            for (int kk = 0; kk < 4; ++kk)
                a1[mt][kk] = *(const short8*)&win[((mp * 2 + mt) * 16 + l16) * SW + kk * 32 + quad * 8];
        const short* wqp = wsb + WS_QKV;
        for (int nt = wq * 6; nt < wq * 6 + 6; ++nt) {
            int n = nt * 16 + l16;
            short8 bfr[4];
            #pragma unroll
            for (int kk = 0; kk < 4; ++kk)
                bfr[kk] = *(const short8*)&wqp[n * Cc + kk * 32 + quad * 8];
            f32x4 c[2];
            c[0] = f32x4{0.f, 0.f, 0.f, 0.f};
            c[1] = f32x4{0.f, 0.f, 0.f, 0.f};
            #pragma unroll
            for (int kk = 0; kk < 4; ++kk)
                #pragma unroll
                for (int mt = 0; mt < 2; ++mt)
                    c[mt] = __builtin_amdgcn_mfma_f32_16x16x32_bf16(a1[mt][kk], bfr[kk], c[mt], 0, 0, 0);
            int g = n >> 7, ch = n & 127, head = ch >> 5, d = ch & 31;
            float bias = qkv_b[n];
            #pragma unroll
            for (int mt = 0; mt < 2; ++mt)
                #pragma unroll
                for (int r = 0; r < 4; ++r) {
                    int tok = (mp * 2 + mt) * 16 + quad * 4 + r;
                    float val = c[mt][r] + bias;
                    if (g == 0)      qk[head * 64 * SQ + tok * SQ + d] = fb(val * 0.17677669529663689f);
                    else if (g == 1) qk[KS_OFF + head * 64 * SQ + tok * SQ + d] = fb(val);
                    else             vT[head * HD * SV + d * SV + tok] = fb(val);
                }
        }
    }
    __syncthreads();

    // ---- preload q/k fragments to registers, then free qs/ks for pm ----
    const int head = wave & 3;
    short8 bk[4], aq[2];
    #pragma unroll
    for (int nt = 0; nt < 4; ++nt)
        bk[nt] = *(const short8*)&qk[KS_OFF + head * 64 * SQ + (nt * 16 + l16) * SQ + quad * 8];
    #pragma unroll
    for (int i = 0; i < 2; ++i)
        aq[i] = *(const short8*)&qk[head * 64 * SQ + ((half * 2 + i) * 16 + l16) * SQ + quad * 8];
    __syncthreads();   // all q/k now in regs; pm may overwrite qk

    // ---- scores + softmax: wave (head,half) handles m-tiles {2*half, 2*half+1} ----
    {
        const float* bT = biasT + head * (Nn * Nn);
        const float* mk = attn_mask + nw * (Nn * Nn);
        #pragma unroll
        for (int i = 0; i < 2; ++i) {
            int mt = half * 2 + i;
            f32x4 sc[4];
            #pragma unroll
            for (int nt = 0; nt < 4; ++nt) {
                f32x4 z = {0.f, 0.f, 0.f, 0.f};
                sc[nt] = __builtin_amdgcn_mfma_f32_16x16x32_bf16(aq[i], bk[nt], z, 0, 0, 0);
            }
            #pragma unroll
            for (int r = 0; r < 4; ++r) {
                int row = mt * 16 + quad * 4 + r;
                bool rowv = row < Nn;
                float v[4];
                #pragma unroll
                for (int nt = 0; nt < 4; ++nt) {
                    int col = nt * 16 + l16;
                    float s = sc[nt][r];
                    if (rowv && col < Nn) s += bT[row * Nn + col] + mk[row * Nn + col];
                    else s = -1e30f;
                    v[nt] = s;
                }
                float mx = fmaxf(fmaxf(v[0], v[1]), fmaxf(v[2], v[3]));
                #pragma unroll
                for (int off = 1; off < 16; off <<= 1) mx = fmaxf(mx, __shfl_xor(mx, off, 64));
                float e[4]; float sum = 0.f;
                #pragma unroll
                for (int nt = 0; nt < 4; ++nt) { e[nt] = __expf(v[nt] - mx); sum += e[nt]; }
                #pragma unroll
                for (int off = 1; off < 16; off <<= 1) sum += __shfl_xor(sum, off, 64);
                float inv = 1.f / sum;
                #pragma unroll
                for (int nt = 0; nt < 4; ++nt)
                    qk[head * 64 * SP + row * SP + nt * 16 + l16] = fb(e[nt] * inv);  // pm alias
            }
        }
    }
    // pm rows for this wave's m-tiles are wave-private; vT stable since QKV barrier.

    // ---- PV: O rows [half*32, half*32+32) x 32 per (head,half) ----
    {
        f32x4 o[2][2];
        #pragma unroll
        for (int i = 0; i < 2; ++i)
            #pragma unroll
            for (int nt = 0; nt < 2; ++nt) o[i][nt] = f32x4{0.f, 0.f, 0.f, 0.f};
        #pragma unroll
        for (int kstep = 0; kstep < 2; ++kstep) {
            short8 bv[2];
            #pragma unroll
            for (int nt = 0; nt < 2; ++nt)
                bv[nt] = *(const short8*)&vT[head * HD * SV + (nt * 16 + l16) * SV + kstep * 32 + quad * 8];
            #pragma unroll
            for (int i = 0; i < 2; ++i) {
                short8 ap = *(const short8*)&qk[head * 64 * SP + ((half * 2 + i) * 16 + l16) * SP + kstep * 32 + quad * 8];
                #pragma unroll
                for (int nt = 0; nt < 2; ++nt)
                    o[i][nt] = __builtin_amdgcn_mfma_f32_16x16x32_bf16(ap, bv[nt], o[i][nt], 0, 0, 0);
            }
        }
        // write attn_out into win (all win reads finished before the post-QKV barrier)
        #pragma unroll
        for (int i = 0; i < 2; ++i)
            #pragma unroll
            for (int nt = 0; nt < 2; ++nt)
                #pragma unroll
                for (int r = 0; r < 4; ++r) {
                    int tok = (half * 2 + i) * 16 + quad * 4 + r;
                    int cch = head * HD + nt * 16 + l16;
                    win[tok * SW + cch] = fb(o[i][nt][r]);
                }
    }
    __syncthreads();

    // ---- proj + residual + scatter: wave (wq,mp): m-tiles {2mp,2mp+1}, n-tiles {wq*2,wq*2+1} ----
    {
        short8 a[2][4];
        #pragma unroll
        for (int mt = 0; mt < 2; ++mt)
            #pragma unroll
            for (int kk = 0; kk < 4; ++kk)
                a[mt][kk] = *(const short8*)&win[((mp * 2 + mt) * 16 + l16) * SW + kk * 32 + quad * 8];
        const short* wp_ = wsb + WS_PROJ;
        for (int nt2 = wq * 2; nt2 < wq * 2 + 2; ++nt2) {
            int n = nt2 * 16 + l16;
            short8 bfr[4];
            #pragma unroll
            for (int kk = 0; kk < 4; ++kk)
                bfr[kk] = *(const short8*)&wp_[n * Cc + kk * 32 + quad * 8];
            f32x4 c[2];
            c[0] = f32x4{0.f, 0.f, 0.f, 0.f};
            c[1] = f32x4{0.f, 0.f, 0.f, 0.f};
            #pragma unroll
            for (int kk = 0; kk < 4; ++kk)
                #pragma unroll
                for (int mt = 0; mt < 2; ++mt)
                    c[mt] = __builtin_amdgcn_mfma_f32_16x16x32_bf16(a[mt][kk], bfr[kk], c[mt], 0, 0, 0);
            float pb = proj_b[n];
            #pragma unroll
            for (int mt = 0; mt < 2; ++mt)
                #pragma unroll
                for (int r = 0; r < 4; ++r) {
                    int tok = (mp * 2 + mt) * 16 + quad * 4 + r;
                    if (tok < Nn) {
                        int i = tok / WS, j = tok - i * WS;
                        int hh = wh * WS + i + SHIFT; if (hh >= Hh) hh -= Hh;
                        int wpp = wwi * WS + j + SHIFT; if (wpp >= Ww) wpp -= Ww;
                        size_t addr = ((size_t)b * (Hh * Ww) + hh * Ww + wpp) * Cc + n;
                        out[addr] = x[addr] + c[mt][r] + pb;
                    }
                }
        }
    }
}

// ---------------- MLP: 128 tokens/block, LN -> fc1 -> GELU -> fc2 -> residual ----------------
// 4 waves, each owns 2 m-tiles (32 tokens) -> every weight fragment feeds 2 MFMA,
// halving weight-load count per MFMA and per-token L2 weight traffic.
#define SH 136   // hb row stride
#define SG 40    // g tile row stride
#define MTOK 128 // tokens per block

__global__ __launch_bounds__(256, 3) void mlp_kernel(
    const float* __restrict__ norm2_w, const float* __restrict__ norm2_b,
    const float* __restrict__ fc1_b,   const float* __restrict__ fc2_b,
    const short* __restrict__ wsb,
    float* __restrict__ xio)
{
    __shared__ short hb[MTOK * SH];        // 34816 B
    __shared__ short gt[NH][32 * SG];      // 10240 B
    __shared__ float b1[HID], b2[Cc];      // 2560 B   -> ~47.6 KB total, 3 blocks/CU

    const int tid  = threadIdx.x;
    const int wave = tid >> 6;
    const int lane = tid & 63;
    const int quad = lane >> 4;
    const int l16  = lane & 15;
    const size_t base = (size_t)blockIdx.x * MTOK * Cc;

    for (int i = tid; i < HID; i += 256) b1[i] = fc1_b[i];
    if (tid < Cc) b2[tid] = fc2_b[tid];

    // ---- LN: 4 threads per token, 2 tokens per thread ----
    #pragma unroll
    for (int rep = 0; rep < 2; ++rep) {
        int t = rep * 64 + (tid >> 2), qtr = tid & 3;
        const float* xr = xio + base + t * Cc + qtr * 32;
        f32x4 v4[8];
        float s1 = 0.f, s2 = 0.f;
        #pragma unroll
        for (int k8 = 0; k8 < 8; ++k8) {
            v4[k8] = *(const f32x4*)&xr[k8 * 4];
            #pragma unroll
            for (int u = 0; u < 4; ++u) { float v = v4[k8][u]; s1 += v; s2 += v * v; }
        }
        s1 += __shfl_xor(s1, 1, 64); s1 += __shfl_xor(s1, 2, 64);
        s2 += __shfl_xor(s2, 1, 64); s2 += __shfl_xor(s2, 2, 64);
        float mu = s1 * (1.f / Cc);
        float var = s2 * (1.f / Cc) - mu * mu;
        float rs = rsqrtf(var + 1e-5f);
        #pragma unroll
        for (int k8 = 0; k8 < 8; ++k8) {
            f32x4 w4 = *(const f32x4*)&norm2_w[qtr * 32 + k8 * 4];
            f32x4 bb4 = *(const f32x4*)&norm2_b[qtr * 32 + k8 * 4];
            s4v o;
            #pragma unroll
            for (int u = 0; u < 4; ++u) o[u] = fb((v4[k8][u] - mu) * rs * w4[u] + bb4[u]);
            *(s4v*)&hb[t * SH + qtr * 32 + k8 * 4] = o;
        }
    }
    __syncthreads();

    // ---- fc1 -> GELU -> fc2 (chunked over hidden), 2 m-tiles per wave ----
    {
        short8 a1[2][4];
        #pragma unroll
        for (int mt = 0; mt < 2; ++mt)
            #pragma unroll
            for (int kk = 0; kk < 4; ++kk)
                a1[mt][kk] = *(const short8*)&hb[((wave * 2 + mt) * 16 + l16) * SH + kk * 32 + quad * 8];
        const short* w1 = wsb + WS_FC1;
        const short* w2 = wsb + WS_FC2;
        f32x4 acc[2][8];
        #pragma unroll
        for (int mt = 0; mt < 2; ++mt)
            #pragma unroll
            for (int n2 = 0; n2 < 8; ++n2) acc[mt][n2] = f32x4{0.f, 0.f, 0.f, 0.f};

        for (int h = 0; h < 16; ++h) {
            #pragma unroll
            for (int nt = 0; nt < 2; ++nt) {
                int n = h * 32 + nt * 16 + l16;
                short8 bfr[4];
                #pragma unroll
                for (int kk = 0; kk < 4; ++kk)
                    bfr[kk] = *(const short8*)&w1[n * Cc + kk * 32 + quad * 8];
                f32x4 c[2];
                c[0] = f32x4{0.f, 0.f, 0.f, 0.f};
                c[1] = f32x4{0.f, 0.f, 0.f, 0.f};
                #pragma unroll
                for (int kk = 0; kk < 4; ++kk)
                    #pragma unroll
                    for (int mt = 0; mt < 2; ++mt)
                        c[mt] = __builtin_amdgcn_mfma_f32_16x16x32_bf16(a1[mt][kk], bfr[kk], c[mt], 0, 0, 0);
                float bb = b1[n];
                #pragma unroll
                for (int mt = 0; mt < 2; ++mt)
                    #pragma unroll
                    for (int r = 0; r < 4; ++r) {
                        float g = fgelu(c[mt][r] + bb);
                        gt[wave][(mt * 16 + quad * 4 + r) * SG + nt * 16 + l16] = fb(g);
                    }
            }
            // wave-private tile: lockstep write->read, no block barrier needed
            short8 a2[2];
            #pragma unroll
            for (int mt = 0; mt < 2; ++mt)
                a2[mt] = *(const short8*)&gt[wave][(mt * 16 + l16) * SG + quad * 8];
            #pragma unroll
            for (int n2 = 0; n2 < 8; ++n2) {
                short8 bfr = *(const short8*)&w2[(n2 * 16 + l16) * HID + h * 32 + quad * 8];
                #pragma unroll
                for (int mt = 0; mt < 2; ++mt)
                    acc[mt][n2] = __builtin_amdgcn_mfma_f32_16x16x32_bf16(a2[mt], bfr, acc[mt][n2], 0, 0, 0);
            }
        }
        // epilogue: + bias + residual, in place
        #pragma unroll
        for (int mt = 0; mt < 2; ++mt)
            #pragma unroll
            for (int n2 = 0; n2 < 8; ++n2) {
                int cch = n2 * 16 + l16;
                float bb = b2[cch];
                #pragma unroll
                for (int r = 0; r < 4; ++r) {
                    int tok = (wave * 2 + mt) * 16 + quad * 4 + r;
                    size_t ad = base + (size_t)tok * Cc + cch;
                    xio[ad] = xio[ad] + acc[mt][n2][r] + bb;
                }
            }
    }
}

extern "C" void kernel_launch(void* const* d_in, const int* in_sizes, int n_in,
                              void* d_out, int out_size, void* d_ws, size_t ws_size,
                              hipStream_t stream) {
    const float* x         = (const float*)d_in[0];
    const float* x_norm1   = (const float*)d_in[1];
    const float* qkv_w     = (const float*)d_in[2];
    const float* qkv_b     = (const float*)d_in[3];
    const float* rel_bias  = (const float*)d_in[4];
    const float* proj_w    = (const float*)d_in[5];
    const float* proj_b    = (const float*)d_in[6];
    const float* norm2_w   = (const float*)d_in[7];
    const float* norm2_b   = (const float*)d_in[8];
    const float* fc1_w     = (const float*)d_in[9];
    const float* fc1_b     = (const float*)d_in[10];
    const float* fc2_w     = (const float*)d_in[11];
    const float* fc2_b     = (const float*)d_in[12];
    const float* attn_mask = (const float*)d_in[13];
    const int*   rel_index = (const int*)d_in[14];
    float* out = (float*)d_out;

    short* wsb   = (short*)d_ws;
    float* biasT = (float*)((char*)d_ws + WS_BIAS_BYTES);

    prep_kernel<<<768, 256, 0, stream>>>(qkv_w, proj_w, fc1_w, fc2_w,
                                         rel_bias, rel_index, wsb, biasT);

    attn_kernel<<<Bb * NW, 512, 0, stream>>>(x, x_norm1, qkv_b, proj_b,
                                             attn_mask, wsb, biasT, out);

    mlp_kernel<<<Bb * Hh * Ww / MTOK, 256, 0, stream>>>(norm2_w, norm2_b, fc1_b,
                                                        fc2_b, wsb, out);
}

// Round 6
// 719.134 us; speedup vs baseline: 1.8800x; 1.0392x over previous
//
#include <hip/hip_runtime.h>
#include <hip/hip_bf16.h>
#include <math.h>

typedef __hip_bfloat16 bf16;
typedef __attribute__((ext_vector_type(8))) short short8;
typedef __attribute__((ext_vector_type(4))) short s4v;
typedef __attribute__((ext_vector_type(4))) float f32x4;

#define Bb 64
#define Hh 56
#define Ww 56
#define Cc 128
#define WS 7
#define SHIFT 3
#define NH 4
#define HD 32
#define Nn 49
#define NW 64
#define HID 512

// ws layout (shorts): qkv_w @0 (49152), proj_w @49152 (16384), fc1_w @65536 (65536), fc2_w @131072 (65536)
// biasT (float) @ byte 393216: [4][49][49]
#define WS_QKV 0
#define WS_PROJ 49152
#define WS_FC1 65536
#define WS_FC2 131072
#define WS_BIAS_BYTES 393216

__device__ __forceinline__ short fb(float v) { return __builtin_bit_cast(short, __float2bfloat16(v)); }

// exp-based tanh GELU: |err| vs exact erf-GELU < 1e-3 absolute (safe vs 0.031 absmax budget).
__device__ __forceinline__ float fgelu(float x) {
    float y = 0.7978845608028654f * (x + 0.044715f * x * x * x);
    float e = __expf(2.f * y);
    float t = 1.f - 2.f / (e + 1.f);
    return 0.5f * x * (1.f + t);
}

// ---------------- prep: weights fp32->bf16 into ws; gather rel-bias table ----------------
__global__ __launch_bounds__(256) void prep_kernel(
    const float* __restrict__ qkv_w, const float* __restrict__ proj_w,
    const float* __restrict__ fc1_w, const float* __restrict__ fc2_w,
    const float* __restrict__ rel_bias, const int* __restrict__ rel_index,
    short* __restrict__ wsb, float* __restrict__ biasT)
{
    int t = blockIdx.x * 256 + threadIdx.x;
    if (t < 49152)       wsb[t] = fb(qkv_w[t]);
    else if (t < 65536)  wsb[t] = fb(proj_w[t - 49152]);
    else if (t < 131072) wsb[t] = fb(fc1_w[t - 65536]);
    else if (t < 196608) wsb[t] = fb(fc2_w[t - 131072]);
    if (t < 4 * Nn * Nn) {
        int h = t / (Nn * Nn), r = t - h * (Nn * Nn);
        biasT[t] = rel_bias[rel_index[r] * NH + h];
    }
}

// ---------------- attention: one block per window, 8 waves (512 thr) ----------------
#define SW 136   // win/ao row stride (128 cols)
#define SQ 40    // qs/ks row stride (32 cols)
#define SV 72    // vT row stride (64 cols)
#define SP 72    // p row stride (64 cols)

// LDS budget: win 17408 B + qk (qs+ks) 40960 B + vT 18432 B = 76800 B -> 2 blocks/CU.
// pm (4*64*SP = 36864 B) ALIASES qk after the q/k register-preload barrier.
__global__ __launch_bounds__(512, 4) void attn_kernel(
    const float* __restrict__ x,          // (B,3136,128) shortcut
    const float* __restrict__ x_norm1,    // (B,3136,128)
    const float* __restrict__ qkv_b,      // (384)
    const float* __restrict__ proj_b,     // (128)
    const float* __restrict__ attn_mask,  // (64,49,49)
    const short* __restrict__ wsb,        // bf16 weights
    const float* __restrict__ biasT,      // (4,49,49)
    float* __restrict__ out)
{
    __shared__ short win[64 * SW];            // window tile; reused as attn_out
    __shared__ short qk[2 * NH * 64 * SQ];    // qs @0, ks @ NH*64*SQ; pm aliases @0
    __shared__ short vT[NH * HD * SV];

    const int blk = blockIdx.x;
    const int b   = blk >> 6;
    const int nw  = blk & 63;
    const int wh  = nw >> 3;
    const int wwi = nw & 7;
    const int tid  = threadIdx.x;
    const int wave = tid >> 6;
    const int lane = tid & 63;
    const int quad = lane >> 4;
    const int l16  = lane & 15;
    const int half = wave >> 2;    // 0/1 split used by score/PV phases
    const int mp   = wave >> 2;    // m-pair for QKV/proj phases
    const int wq   = wave & 3;     // n-slice for QKV/proj phases

    const int KS_OFF = NH * 64 * SQ;   // ks base inside qk

    // ---- gather shifted window, float4-vectorized (rows 49..63 zero) ----
    #pragma unroll
    for (int it = 0; it < 4; ++it) {
        int idx = it * 512 + tid;
        int t = idx >> 5, c4 = (idx & 31) * 4;
        f32x4 v = {0.f, 0.f, 0.f, 0.f};
        if (t < Nn) {
            int i = t / WS, j = t - i * WS;
            int hh = wh * WS + i + SHIFT; if (hh >= Hh) hh -= Hh;
            int wp = wwi * WS + j + SHIFT; if (wp >= Ww) wp -= Ww;
            v = *(const f32x4*)&x_norm1[((size_t)b * (Hh * Ww) + hh * Ww + wp) * Cc + c4];
        }
        s4v sv;
        #pragma unroll
        for (int u = 0; u < 4; ++u) sv[u] = fb(v[u]);
        *(s4v*)&win[t * SW + c4] = sv;
    }
    __syncthreads();

    // ---- QKV: wave (wq,mp): m-tiles {2mp,2mp+1}, n-tiles nt=j*4+wq, j=0..5 ----
    // j<2 -> Q, j<4 -> K, else V: compile-time group per unrolled j (branch-free epilogues).
    {
        short8 a1[2][4];
        #pragma unroll
        for (int mt = 0; mt < 2; ++mt)
            #pragma unroll
            for (int kk = 0; kk < 4; ++kk)
                a1[mt][kk] = *(const short8*)&win[((mp * 2 + mt) * 16 + l16) * SW + kk * 32 + quad * 8];
        const short* wqp = wsb + WS_QKV;
        float bias6[6];
        #pragma unroll
        for (int j = 0; j < 6; ++j) bias6[j] = qkv_b[(j * 4 + wq) * 16 + l16];
        const int dcol = (wq & 1) * 16 + l16;          // d for q/k/v targets
        #pragma unroll
        for (int j = 0; j < 6; ++j) {
            const int nt = j * 4 + wq;
            const int n = nt * 16 + l16;
            short8 bfr[4];
            #pragma unroll
            for (int kk = 0; kk < 4; ++kk)
                bfr[kk] = *(const short8*)&wqp[n * Cc + kk * 32 + quad * 8];
            f32x4 c[2];
            c[0] = f32x4{0.f, 0.f, 0.f, 0.f};
            c[1] = f32x4{0.f, 0.f, 0.f, 0.f};
            #pragma unroll
            for (int kk = 0; kk < 4; ++kk)
                #pragma unroll
                for (int mt = 0; mt < 2; ++mt)
                    c[mt] = __builtin_amdgcn_mfma_f32_16x16x32_bf16(a1[mt][kk], bfr[kk], c[mt], 0, 0, 0);
            const int head = (wq >> 1) + 2 * (j & 1);  // = ((nt&7)>>1)
            const float bias = bias6[j];
            #pragma unroll
            for (int mt = 0; mt < 2; ++mt)
                #pragma unroll
                for (int r = 0; r < 4; ++r) {
                    int tok = (mp * 2 + mt) * 16 + quad * 4 + r;
                    float val = c[mt][r] + bias;
                    if (j < 2)      qk[head * 64 * SQ + tok * SQ + dcol] = fb(val * 0.17677669529663689f);
                    else if (j < 4) qk[KS_OFF + head * 64 * SQ + tok * SQ + dcol] = fb(val);
                    else            vT[head * HD * SV + dcol * SV + tok] = fb(val);
                }
        }
    }
    __syncthreads();

    // ---- preload q/k fragments to registers, then free qs/ks for pm ----
    const int head = wave & 3;
    short8 bk[4], aq[2];
    #pragma unroll
    for (int nt = 0; nt < 4; ++nt)
        bk[nt] = *(const short8*)&qk[KS_OFF + head * 64 * SQ + (nt * 16 + l16) * SQ + quad * 8];
    #pragma unroll
    for (int i = 0; i < 2; ++i)
        aq[i] = *(const short8*)&qk[head * 64 * SQ + ((half * 2 + i) * 16 + l16) * SQ + quad * 8];
    __syncthreads();   // all q/k now in regs; pm may overwrite qk

    // ---- scores + softmax: wave (head,half) handles m-tiles {2*half, 2*half+1} ----
    {
        const float* bT = biasT + head * (Nn * Nn);
        const float* mk = attn_mask + nw * (Nn * Nn);
        #pragma unroll
        for (int i = 0; i < 2; ++i) {
            int mt = half * 2 + i;
            // prefetch bias+mask (independent of the MFMAs below -> overlaps L2 latency)
            float bm[4][4];
            #pragma unroll
            for (int r = 0; r < 4; ++r) {
                int row = mt * 16 + quad * 4 + r;
                bool rowv = row < Nn;
                int rb = row * Nn;
                #pragma unroll
                for (int nt = 0; nt < 4; ++nt) {
                    int col = nt * 16 + l16;
                    bm[r][nt] = (rowv && col < Nn) ? (bT[rb + col] + mk[rb + col]) : -1e30f;
                }
            }
            f32x4 sc[4];
            #pragma unroll
            for (int nt = 0; nt < 4; ++nt) {
                f32x4 z = {0.f, 0.f, 0.f, 0.f};
                sc[nt] = __builtin_amdgcn_mfma_f32_16x16x32_bf16(aq[i], bk[nt], z, 0, 0, 0);
            }
            #pragma unroll
            for (int r = 0; r < 4; ++r) {
                int row = mt * 16 + quad * 4 + r;
                float v[4];
                #pragma unroll
                for (int nt = 0; nt < 4; ++nt) v[nt] = sc[nt][r] + bm[r][nt];
                float mx = fmaxf(fmaxf(v[0], v[1]), fmaxf(v[2], v[3]));
                #pragma unroll
                for (int off = 1; off < 16; off <<= 1) mx = fmaxf(mx, __shfl_xor(mx, off, 64));
                float e[4]; float sum = 0.f;
                #pragma unroll
                for (int nt = 0; nt < 4; ++nt) { e[nt] = __expf(v[nt] - mx); sum += e[nt]; }
                #pragma unroll
                for (int off = 1; off < 16; off <<= 1) sum += __shfl_xor(sum, off, 64);
                float inv = 1.f / sum;
                #pragma unroll
                for (int nt = 0; nt < 4; ++nt)
                    qk[head * 64 * SP + row * SP + nt * 16 + l16] = fb(e[nt] * inv);  // pm alias
            }
        }
    }
    // pm rows for this wave's m-tiles are wave-private; vT stable since QKV barrier.

    // ---- PV: O rows [half*32, half*32+32) x 32 per (head,half) ----
    {
        f32x4 o[2][2];
        #pragma unroll
        for (int i = 0; i < 2; ++i)
            #pragma unroll
            for (int nt = 0; nt < 2; ++nt) o[i][nt] = f32x4{0.f, 0.f, 0.f, 0.f};
        #pragma unroll
        for (int kstep = 0; kstep < 2; ++kstep) {
            short8 bv[2];
            #pragma unroll
            for (int nt = 0; nt < 2; ++nt)
                bv[nt] = *(const short8*)&vT[head * HD * SV + (nt * 16 + l16) * SV + kstep * 32 + quad * 8];
            #pragma unroll
            for (int i = 0; i < 2; ++i) {
                short8 ap = *(const short8*)&qk[head * 64 * SP + ((half * 2 + i) * 16 + l16) * SP + kstep * 32 + quad * 8];
                #pragma unroll
                for (int nt = 0; nt < 2; ++nt)
                    o[i][nt] = __builtin_amdgcn_mfma_f32_16x16x32_bf16(ap, bv[nt], o[i][nt], 0, 0, 0);
            }
        }
        #pragma unroll
        for (int i = 0; i < 2; ++i)
            #pragma unroll
            for (int nt = 0; nt < 2; ++nt)
                #pragma unroll
                for (int r = 0; r < 4; ++r) {
                    int tok = (half * 2 + i) * 16 + quad * 4 + r;
                    int cch = head * HD + nt * 16 + l16;
                    win[tok * SW + cch] = fb(o[i][nt][r]);
                }
    }
    __syncthreads();

    // ---- proj + residual + scatter: wave (wq,mp): m-tiles {2mp,2mp+1}, n-tiles {wq*2,wq*2+1} ----
    // MFMAs for both n-tiles first, then one address-calc per (mt,r) with both column stores.
    {
        short8 a[2][4];
        #pragma unroll
        for (int mt = 0; mt < 2; ++mt)
            #pragma unroll
            for (int kk = 0; kk < 4; ++kk)
                a[mt][kk] = *(const short8*)&win[((mp * 2 + mt) * 16 + l16) * SW + kk * 32 + quad * 8];
        const short* wp_ = wsb + WS_PROJ;
        float pb2[2];
        #pragma unroll
        for (int j2 = 0; j2 < 2; ++j2) pb2[j2] = proj_b[(wq * 2 + j2) * 16 + l16];
        f32x4 c2[2][2];
        #pragma unroll
        for (int j2 = 0; j2 < 2; ++j2) {
            c2[j2][0] = f32x4{0.f, 0.f, 0.f, 0.f};
            c2[j2][1] = f32x4{0.f, 0.f, 0.f, 0.f};
            const int n = (wq * 2 + j2) * 16 + l16;
            short8 bfr[4];
            #pragma unroll
            for (int kk = 0; kk < 4; ++kk)
                bfr[kk] = *(const short8*)&wp_[n * Cc + kk * 32 + quad * 8];
            #pragma unroll
            for (int kk = 0; kk < 4; ++kk)
                #pragma unroll
                for (int mt = 0; mt < 2; ++mt)
                    c2[j2][mt] = __builtin_amdgcn_mfma_f32_16x16x32_bf16(a[mt][kk], bfr[kk], c2[j2][mt], 0, 0, 0);
        }
        #pragma unroll
        for (int mt = 0; mt < 2; ++mt)
            #pragma unroll
            for (int r = 0; r < 4; ++r) {
                int tok = (mp * 2 + mt) * 16 + quad * 4 + r;
                if (tok < Nn) {
                    int i = tok / WS, j = tok - i * WS;
                    int hh = wh * WS + i + SHIFT; if (hh >= Hh) hh -= Hh;
                    int wpp = wwi * WS + j + SHIFT; if (wpp >= Ww) wpp -= Ww;
                    size_t ab = ((size_t)b * (Hh * Ww) + hh * Ww + wpp) * Cc;
                    #pragma unroll
                    for (int j2 = 0; j2 < 2; ++j2) {
                        size_t addr = ab + (wq * 2 + j2) * 16 + l16;
                        out[addr] = x[addr] + c2[j2][mt][r] + pb2[j2];
                    }
                }
            }
    }
}

// ---------------- MLP: 128 tokens/block, LN -> fc1 -> GELU -> fc2 -> residual ----------------
#define SH 136   // hb row stride
#define SG 40    // g tile row stride
#define MTOK 128 // tokens per block

__global__ __launch_bounds__(256, 3) void mlp_kernel(
    const float* __restrict__ norm2_w, const float* __restrict__ norm2_b,
    const float* __restrict__ fc1_b,   const float* __restrict__ fc2_b,
    const short* __restrict__ wsb,
    float* __restrict__ xio)
{
    __shared__ short hb[MTOK * SH];        // 34816 B
    __shared__ short gt[NH][32 * SG];      // 10240 B
    __shared__ float b1[HID], b2[Cc];      // 2560 B   -> ~47.6 KB total, 3 blocks/CU

    const int tid  = threadIdx.x;
    const int wave = tid >> 6;
    const int lane = tid & 63;
    const int quad = lane >> 4;
    const int l16  = lane & 15;
    const size_t base = (size_t)blockIdx.x * MTOK * Cc;

    for (int i = tid; i < HID; i += 256) b1[i] = fc1_b[i];
    if (tid < Cc) b2[tid] = fc2_b[tid];

    // ---- LN: 4 threads per token, 2 tokens per thread ----
    #pragma unroll
    for (int rep = 0; rep < 2; ++rep) {
        int t = rep * 64 + (tid >> 2), qtr = tid & 3;
        const float* xr = xio + base + t * Cc + qtr * 32;
        f32x4 v4[8];
        float s1 = 0.f, s2 = 0.f;
        #pragma unroll
        for (int k8 = 0; k8 < 8; ++k8) {
            v4[k8] = *(const f32x4*)&xr[k8 * 4];
            #pragma unroll
            for (int u = 0; u < 4; ++u) { float v = v4[k8][u]; s1 += v; s2 += v * v; }
        }
        s1 += __shfl_xor(s1, 1, 64); s1 += __shfl_xor(s1, 2, 64);
        s2 += __shfl_xor(s2, 1, 64); s2 += __shfl_xor(s2, 2, 64);
        float mu = s1 * (1.f / Cc);
        float var = s2 * (1.f / Cc) - mu * mu;
        float rs = rsqrtf(var + 1e-5f);
        #pragma unroll
        for (int k8 = 0; k8 < 8; ++k8) {
            f32x4 w4 = *(const f32x4*)&norm2_w[qtr * 32 + k8 * 4];
            f32x4 bb4 = *(const f32x4*)&norm2_b[qtr * 32 + k8 * 4];
            s4v o;
            #pragma unroll
            for (int u = 0; u < 4; ++u) o[u] = fb((v4[k8][u] - mu) * rs * w4[u] + bb4[u]);
            *(s4v*)&hb[t * SH + qtr * 32 + k8 * 4] = o;
        }
    }
    __syncthreads();

    // ---- fc1 -> GELU -> fc2 (chunked over hidden), 2 m-tiles per wave ----
    {
        short8 a1[2][4];
        #pragma unroll
        for (int mt = 0; mt < 2; ++mt)
            #pragma unroll
            for (int kk = 0; kk < 4; ++kk)
                a1[mt][kk] = *(const short8*)&hb[((wave * 2 + mt) * 16 + l16) * SH + kk * 32 + quad * 8];
        const short* w1 = wsb + WS_FC1;
        const short* w2 = wsb + WS_FC2;
        f32x4 acc[2][8];
        #pragma unroll
        for (int mt = 0; mt < 2; ++mt)
            #pragma unroll
            for (int n2 = 0; n2 < 8; ++n2) acc[mt][n2] = f32x4{0.f, 0.f, 0.f, 0.f};

        for (int h = 0; h < 16; ++h) {
            #pragma unroll
            for (int nt = 0; nt < 2; ++nt) {
                int n = h * 32 + nt * 16 + l16;
                short8 bfr[4];
                #pragma unroll
                for (int kk = 0; kk < 4; ++kk)
                    bfr[kk] = *(const short8*)&w1[n * Cc + kk * 32 + quad * 8];
                f32x4 c[2];
                c[0] = f32x4{0.f, 0.f, 0.f, 0.f};
                c[1] = f32x4{0.f, 0.f, 0.f, 0.f};
                #pragma unroll
                for (int kk = 0; kk < 4; ++kk)
                    #pragma unroll
                    for (int mt = 0; mt < 2; ++mt)
                        c[mt] = __builtin_amdgcn_mfma_f32_16x16x32_bf16(a1[mt][kk], bfr[kk], c[mt], 0, 0, 0);
                float bb = b1[n];
                #pragma unroll
                for (int mt = 0; mt < 2; ++mt)
                    #pragma unroll
                    for (int r = 0; r < 4; ++r) {
                        float g = fgelu(c[mt][r] + bb);
                        gt[wave][(mt * 16 + quad * 4 + r) * SG + nt * 16 + l16] = fb(g);
                    }
            }
            // wave-private tile: lockstep write->read, no block barrier needed
            short8 a2[2];
            #pragma unroll
            for (int mt = 0; mt < 2; ++mt)
                a2[mt] = *(const short8*)&gt[wave][(mt * 16 + l16) * SG + quad * 8];
            #pragma unroll
            for (int n2 = 0; n2 < 8; ++n2) {
                short8 bfr = *(const short8*)&w2[(n2 * 16 + l16) * HID + h * 32 + quad * 8];
                #pragma unroll
                for (int mt = 0; mt < 2; ++mt)
                    acc[mt][n2] = __builtin_amdgcn_mfma_f32_16x16x32_bf16(a2[mt], bfr, acc[mt][n2], 0, 0, 0);
            }
        }
        // epilogue: + bias + residual, in place
        #pragma unroll
        for (int mt = 0; mt < 2; ++mt)
            #pragma unroll
            for (int n2 = 0; n2 < 8; ++n2) {
                int cch = n2 * 16 + l16;
                float bb = b2[cch];
                #pragma unroll
                for (int r = 0; r < 4; ++r) {
                    int tok = (wave * 2 + mt) * 16 + quad * 4 + r;
                    size_t ad = base + (size_t)tok * Cc + cch;
                    xio[ad] = xio[ad] + acc[mt][n2][r] + bb;
                }
            }
    }
}

extern "C" void kernel_launch(void* const* d_in, const int* in_sizes, int n_in,
                              void* d_out, int out_size, void* d_ws, size_t ws_size,
                              hipStream_t stream) {
    const float* x         = (const float*)d_in[0];
    const float* x_norm1   = (const float*)d_in[1];
    const float* qkv_w     = (const float*)d_in[2];
    const float* qkv_b     = (const float*)d_in[3];
    const float* rel_bias  = (const float*)d_in[4];
    const float* proj_w    = (const float*)d_in[5];
    const float* proj_b    = (const float*)d_in[6];
    const float* norm2_w   = (const float*)d_in[7];
    const float* norm2_b   = (const float*)d_in[8];
    const float* fc1_w     = (const float*)d_in[9];
    const float* fc1_b     = (const float*)d_in[10];
    const float* fc2_w     = (const float*)d_in[11];
    const float* fc2_b     = (const float*)d_in[12];
    const float* attn_mask = (const float*)d_in[13];
    const int*   rel_index = (const int*)d_in[14];
    float* out = (float*)d_out;

    short* wsb   = (short*)d_ws;
    float* biasT = (float*)((char*)d_ws + WS_BIAS_BYTES);

    prep_kernel<<<768, 256, 0, stream>>>(qkv_w, proj_w, fc1_w, fc2_w,
                                         rel_bias, rel_index, wsb, biasT);

    attn_kernel<<<Bb * NW, 512, 0, stream>>>(x, x_norm1, qkv_b, proj_b,
                                             attn_mask, wsb, biasT, out);

    mlp_kernel<<<Bb * Hh * Ww / MTOK, 256, 0, stream>>>(norm2_w, norm2_b, fc1_b,
                                                        fc2_b, wsb, out);
}

// Round 7
// 698.969 us; speedup vs baseline: 1.9342x; 1.0288x over previous
//
#include <hip/hip_runtime.h>
#include <hip/hip_bf16.h>
#include <math.h>

typedef __hip_bfloat16 bf16;
typedef __attribute__((ext_vector_type(8))) short short8;
typedef __attribute__((ext_vector_type(4))) short s4v;
typedef __attribute__((ext_vector_type(4))) float f32x4;

#define Bb 64
#define Hh 56
#define Ww 56
#define Cc 128
#define WS 7
#define SHIFT 3
#define NH 4
#define HD 32
#define Nn 49
#define NW 64
#define HID 512

// ws layout (shorts): qkv_w @0 (49152), proj_w @49152 (16384), fc1_w @65536 (65536), fc2_w @131072 (65536)
// biasT (float) @ byte 393216: [4][49][49]
#define WS_QKV 0
#define WS_PROJ 49152
#define WS_FC1 65536
#define WS_FC2 131072
#define WS_BIAS_BYTES 393216

__device__ __forceinline__ short fb(float v) { return __builtin_bit_cast(short, __float2bfloat16(v)); }

// fast approximate reciprocal (v_rcp_f32, ~2^-22 rel err — fine for bf16 outputs);
// avoids the IEEE div_scale/div_fmas/div_fixup sequence (~10 instr) per division.
__device__ __forceinline__ float frcp(float d) {
    float r;
    asm("v_rcp_f32 %0, %1" : "=v"(r) : "v"(d));
    return r;
}

// exp-based tanh GELU, division-free: gelu = x - x/(e^{2y}+1), 2y = A*x + B*x^3.
// |err| vs exact erf-GELU < 1e-3 absolute (safe vs 0.031 absmax budget).
// Overflow-safe: e=inf -> r=0 -> g=x; e=0 -> r=1 -> g=0.
__device__ __forceinline__ float fgelu(float x) {
    float z = x * x;
    float u = fmaf(z, 0.0713537069f, 1.5957691216f);   // (2y)/x
    float e = __expf(u * x);
    float r = frcp(e + 1.f);
    return fmaf(-x, r, x);
}

// ---------------- prep: weights fp32->bf16 into ws; gather rel-bias table ----------------
__global__ __launch_bounds__(256) void prep_kernel(
    const float* __restrict__ qkv_w, const float* __restrict__ proj_w,
    const float* __restrict__ fc1_w, const float* __restrict__ fc2_w,
    const float* __restrict__ rel_bias, const int* __restrict__ rel_index,
    short* __restrict__ wsb, float* __restrict__ biasT)
{
    int t = blockIdx.x * 256 + threadIdx.x;
    if (t < 49152)       wsb[t] = fb(qkv_w[t]);
    else if (t < 65536)  wsb[t] = fb(proj_w[t - 49152]);
    else if (t < 131072) wsb[t] = fb(fc1_w[t - 65536]);
    else if (t < 196608) wsb[t] = fb(fc2_w[t - 131072]);
    if (t < 4 * Nn * Nn) {
        int h = t / (Nn * Nn), r = t - h * (Nn * Nn);
        biasT[t] = rel_bias[rel_index[r] * NH + h];
    }
}

// ---------------- attention: one block per window, 8 waves (512 thr) ----------------
#define SW 136   // win/ao row stride (128 cols)
#define SQ 40    // qs/ks row stride (32 cols)
#define SV 72    // vT row stride (64 cols)
#define SP 72    // p row stride (64 cols)

// LDS budget: win 17408 B + qk (qs+ks) 40960 B + vT 18432 B = 76800 B -> 2 blocks/CU.
// pm (4*64*SP = 36864 B) ALIASES qk after the q/k register-preload barrier.
__global__ __launch_bounds__(512, 4) void attn_kernel(
    const float* __restrict__ x,          // (B,3136,128) shortcut
    const float* __restrict__ x_norm1,    // (B,3136,128)
    const float* __restrict__ qkv_b,      // (384)
    const float* __restrict__ proj_b,     // (128)
    const float* __restrict__ attn_mask,  // (64,49,49)
    const short* __restrict__ wsb,        // bf16 weights
    const float* __restrict__ biasT,      // (4,49,49)
    float* __restrict__ out)
{
    __shared__ short win[64 * SW];            // window tile; reused as attn_out
    __shared__ short qk[2 * NH * 64 * SQ];    // qs @0, ks @ NH*64*SQ; pm aliases @0
    __shared__ short vT[NH * HD * SV];

    const int blk = blockIdx.x;
    const int b   = blk >> 6;
    const int nw  = blk & 63;
    const int wh  = nw >> 3;
    const int wwi = nw & 7;
    const int tid  = threadIdx.x;
    const int wave = tid >> 6;
    const int lane = tid & 63;
    const int quad = lane >> 4;
    const int l16  = lane & 15;
    const int half = wave >> 2;    // 0/1 split used by score/PV phases
    const int mp   = wave >> 2;    // m-pair for QKV/proj phases
    const int wq   = wave & 3;     // n-slice for QKV/proj phases

    const int KS_OFF = NH * 64 * SQ;   // ks base inside qk

    // ---- gather shifted window, float4-vectorized (rows 49..63 zero) ----
    #pragma unroll
    for (int it = 0; it < 4; ++it) {
        int idx = it * 512 + tid;
        int t = idx >> 5, c4 = (idx & 31) * 4;
        f32x4 v = {0.f, 0.f, 0.f, 0.f};
        if (t < Nn) {
            int i = t / WS, j = t - i * WS;
            int hh = wh * WS + i + SHIFT; if (hh >= Hh) hh -= Hh;
            int wp = wwi * WS + j + SHIFT; if (wp >= Ww) wp -= Ww;
            v = *(const f32x4*)&x_norm1[((size_t)b * (Hh * Ww) + hh * Ww + wp) * Cc + c4];
        }
        s4v sv;
        #pragma unroll
        for (int u = 0; u < 4; ++u) sv[u] = fb(v[u]);
        *(s4v*)&win[t * SW + c4] = sv;
    }
    __syncthreads();

    // ---- QKV: wave (wq,mp): m-tiles {2mp,2mp+1}, n-tiles nt=j*4+wq, j=0..5 ----
    // j<2 -> Q, j<4 -> K, else V: compile-time group per unrolled j (branch-free epilogues).
    {
        short8 a1[2][4];
        #pragma unroll
        for (int mt = 0; mt < 2; ++mt)
            #pragma unroll
            for (int kk = 0; kk < 4; ++kk)
                a1[mt][kk] = *(const short8*)&win[((mp * 2 + mt) * 16 + l16) * SW + kk * 32 + quad * 8];
        const short* wqp = wsb + WS_QKV;
        float bias6[6];
        #pragma unroll
        for (int j = 0; j < 6; ++j) bias6[j] = qkv_b[(j * 4 + wq) * 16 + l16];
        const int dcol = (wq & 1) * 16 + l16;          // d for q/k/v targets
        #pragma unroll
        for (int j = 0; j < 6; ++j) {
            const int nt = j * 4 + wq;
            const int n = nt * 16 + l16;
            short8 bfr[4];
            #pragma unroll
            for (int kk = 0; kk < 4; ++kk)
                bfr[kk] = *(const short8*)&wqp[n * Cc + kk * 32 + quad * 8];
            f32x4 c[2];
            c[0] = f32x4{0.f, 0.f, 0.f, 0.f};
            c[1] = f32x4{0.f, 0.f, 0.f, 0.f};
            #pragma unroll
            for (int kk = 0; kk < 4; ++kk)
                #pragma unroll
                for (int mt = 0; mt < 2; ++mt)
                    c[mt] = __builtin_amdgcn_mfma_f32_16x16x32_bf16(a1[mt][kk], bfr[kk], c[mt], 0, 0, 0);
            const int head = (wq >> 1) + 2 * (j & 1);  // = ((nt&7)>>1)
            const float bias = bias6[j];
            #pragma unroll
            for (int mt = 0; mt < 2; ++mt)
                #pragma unroll
                for (int r = 0; r < 4; ++r) {
                    int tok = (mp * 2 + mt) * 16 + quad * 4 + r;
                    float val = c[mt][r] + bias;
                    if (j < 2)      qk[head * 64 * SQ + tok * SQ + dcol] = fb(val * 0.17677669529663689f);
                    else if (j < 4) qk[KS_OFF + head * 64 * SQ + tok * SQ + dcol] = fb(val);
                    else            vT[head * HD * SV + dcol * SV + tok] = fb(val);
                }
        }
    }
    __syncthreads();

    // ---- preload q/k fragments to registers, then free qs/ks for pm ----
    const int head = wave & 3;
    short8 bk[4], aq[2];
    #pragma unroll
    for (int nt = 0; nt < 4; ++nt)
        bk[nt] = *(const short8*)&qk[KS_OFF + head * 64 * SQ + (nt * 16 + l16) * SQ + quad * 8];
    #pragma unroll
    for (int i = 0; i < 2; ++i)
        aq[i] = *(const short8*)&qk[head * 64 * SQ + ((half * 2 + i) * 16 + l16) * SQ + quad * 8];
    __syncthreads();   // all q/k now in regs; pm may overwrite qk

    // ---- scores + softmax: wave (head,half) handles m-tiles {2*half, 2*half+1} ----
    {
        const float* bT = biasT + head * (Nn * Nn);
        const float* mk = attn_mask + nw * (Nn * Nn);
        #pragma unroll
        for (int i = 0; i < 2; ++i) {
            int mt = half * 2 + i;
            // prefetch bias+mask (independent of the MFMAs below -> overlaps L2 latency)
            float bm[4][4];
            #pragma unroll
            for (int r = 0; r < 4; ++r) {
                int row = mt * 16 + quad * 4 + r;
                bool rowv = row < Nn;
                int rb = row * Nn;
                #pragma unroll
                for (int nt = 0; nt < 4; ++nt) {
                    int col = nt * 16 + l16;
                    bm[r][nt] = (rowv && col < Nn) ? (bT[rb + col] + mk[rb + col]) : -1e30f;
                }
            }
            f32x4 sc[4];
            #pragma unroll
            for (int nt = 0; nt < 4; ++nt) {
                f32x4 z = {0.f, 0.f, 0.f, 0.f};
                sc[nt] = __builtin_amdgcn_mfma_f32_16x16x32_bf16(aq[i], bk[nt], z, 0, 0, 0);
            }
            #pragma unroll
            for (int r = 0; r < 4; ++r) {
                int row = mt * 16 + quad * 4 + r;
                float v[4];
                #pragma unroll
                for (int nt = 0; nt < 4; ++nt) v[nt] = sc[nt][r] + bm[r][nt];
                float mx = fmaxf(fmaxf(v[0], v[1]), fmaxf(v[2], v[3]));
                #pragma unroll
                for (int off = 1; off < 16; off <<= 1) mx = fmaxf(mx, __shfl_xor(mx, off, 64));
                float e[4]; float sum = 0.f;
                #pragma unroll
                for (int nt = 0; nt < 4; ++nt) { e[nt] = __expf(v[nt] - mx); sum += e[nt]; }
                #pragma unroll
                for (int off = 1; off < 16; off <<= 1) sum += __shfl_xor(sum, off, 64);
                float inv = frcp(sum);
                #pragma unroll
                for (int nt = 0; nt < 4; ++nt)
                    qk[head * 64 * SP + row * SP + nt * 16 + l16] = fb(e[nt] * inv);  // pm alias
            }
        }
    }
    // pm rows for this wave's m-tiles are wave-private; vT stable since QKV barrier.

    // ---- PV: O rows [half*32, half*32+32) x 32 per (head,half) ----
    {
        f32x4 o[2][2];
        #pragma unroll
        for (int i = 0; i < 2; ++i)
            #pragma unroll
            for (int nt = 0; nt < 2; ++nt) o[i][nt] = f32x4{0.f, 0.f, 0.f, 0.f};
        #pragma unroll
        for (int kstep = 0; kstep < 2; ++kstep) {
            short8 bv[2];
            #pragma unroll
            for (int nt = 0; nt < 2; ++nt)
                bv[nt] = *(const short8*)&vT[head * HD * SV + (nt * 16 + l16) * SV + kstep * 32 + quad * 8];
            #pragma unroll
            for (int i = 0; i < 2; ++i) {
                short8 ap = *(const short8*)&qk[head * 64 * SP + ((half * 2 + i) * 16 + l16) * SP + kstep * 32 + quad * 8];
                #pragma unroll
                for (int nt = 0; nt < 2; ++nt)
                    o[i][nt] = __builtin_amdgcn_mfma_f32_16x16x32_bf16(ap, bv[nt], o[i][nt], 0, 0, 0);
            }
        }
        #pragma unroll
        for (int i = 0; i < 2; ++i)
            #pragma unroll
            for (int nt = 0; nt < 2; ++nt)
                #pragma unroll
                for (int r = 0; r < 4; ++r) {
                    int tok = (half * 2 + i) * 16 + quad * 4 + r;
                    int cch = head * HD + nt * 16 + l16;
                    win[tok * SW + cch] = fb(o[i][nt][r]);
                }
    }
    __syncthreads();

    // ---- proj + residual + scatter: wave (wq,mp): m-tiles {2mp,2mp+1}, n-tiles {wq*2,wq*2+1} ----
    {
        short8 a[2][4];
        #pragma unroll
        for (int mt = 0; mt < 2; ++mt)
            #pragma unroll
            for (int kk = 0; kk < 4; ++kk)
                a[mt][kk] = *(const short8*)&win[((mp * 2 + mt) * 16 + l16) * SW + kk * 32 + quad * 8];
        const short* wp_ = wsb + WS_PROJ;
        float pb2[2];
        #pragma unroll
        for (int j2 = 0; j2 < 2; ++j2) pb2[j2] = proj_b[(wq * 2 + j2) * 16 + l16];
        f32x4 c2[2][2];
        #pragma unroll
        for (int j2 = 0; j2 < 2; ++j2) {
            c2[j2][0] = f32x4{0.f, 0.f, 0.f, 0.f};
            c2[j2][1] = f32x4{0.f, 0.f, 0.f, 0.f};
            const int n = (wq * 2 + j2) * 16 + l16;
            short8 bfr[4];
            #pragma unroll
            for (int kk = 0; kk < 4; ++kk)
                bfr[kk] = *(const short8*)&wp_[n * Cc + kk * 32 + quad * 8];
            #pragma unroll
            for (int kk = 0; kk < 4; ++kk)
                #pragma unroll
                for (int mt = 0; mt < 2; ++mt)
                    c2[j2][mt] = __builtin_amdgcn_mfma_f32_16x16x32_bf16(a[mt][kk], bfr[kk], c2[j2][mt], 0, 0, 0);
        }
        #pragma unroll
        for (int mt = 0; mt < 2; ++mt)
            #pragma unroll
            for (int r = 0; r < 4; ++r) {
                int tok = (mp * 2 + mt) * 16 + quad * 4 + r;
                if (tok < Nn) {
                    int i = tok / WS, j = tok - i * WS;
                    int hh = wh * WS + i + SHIFT; if (hh >= Hh) hh -= Hh;
                    int wpp = wwi * WS + j + SHIFT; if (wpp >= Ww) wpp -= Ww;
                    size_t ab = ((size_t)b * (Hh * Ww) + hh * Ww + wpp) * Cc;
                    #pragma unroll
                    for (int j2 = 0; j2 < 2; ++j2) {
                        size_t addr = ab + (wq * 2 + j2) * 16 + l16;
                        out[addr] = x[addr] + c2[j2][mt][r] + pb2[j2];
                    }
                }
            }
    }
}

// ---------------- MLP: 128 tokens/block, LN -> fc1 -> GELU -> fc2 -> residual ----------------
// gt ALIASES hb (hb is dead after the a1 fragment preload + barrier):
// LDS = 34816 (hb) + 2560 (b1,b2) = 37376 B -> 4 blocks/CU (16 waves).
#define SH 136   // hb row stride
#define SG 40    // g tile row stride
#define MTOK 128 // tokens per block

__global__ __launch_bounds__(256, 4) void mlp_kernel(
    const float* __restrict__ norm2_w, const float* __restrict__ norm2_b,
    const float* __restrict__ fc1_b,   const float* __restrict__ fc2_b,
    const short* __restrict__ wsb,
    float* __restrict__ xio)
{
    __shared__ short hb[MTOK * SH];        // 34816 B; gt aliases the front of this
    __shared__ float b1[HID], b2[Cc];      // 2560 B

    const int tid  = threadIdx.x;
    const int wave = tid >> 6;
    const int lane = tid & 63;
    const int quad = lane >> 4;
    const int l16  = lane & 15;
    const size_t base = (size_t)blockIdx.x * MTOK * Cc;

    for (int i = tid; i < HID; i += 256) b1[i] = fc1_b[i];
    if (tid < Cc) b2[tid] = fc2_b[tid];

    // ---- LN: 4 threads per token, 2 tokens per thread ----
    #pragma unroll
    for (int rep = 0; rep < 2; ++rep) {
        int t = rep * 64 + (tid >> 2), qtr = tid & 3;
        const float* xr = xio + base + t * Cc + qtr * 32;
        f32x4 v4[8];
        float s1 = 0.f, s2 = 0.f;
        #pragma unroll
        for (int k8 = 0; k8 < 8; ++k8) {
            v4[k8] = *(const f32x4*)&xr[k8 * 4];
            #pragma unroll
            for (int u = 0; u < 4; ++u) { float v = v4[k8][u]; s1 += v; s2 += v * v; }
        }
        s1 += __shfl_xor(s1, 1, 64); s1 += __shfl_xor(s1, 2, 64);
        s2 += __shfl_xor(s2, 1, 64); s2 += __shfl_xor(s2, 2, 64);
        float mu = s1 * (1.f / Cc);
        float var = s2 * (1.f / Cc) - mu * mu;
        float rs = rsqrtf(var + 1e-5f);
        #pragma unroll
        for (int k8 = 0; k8 < 8; ++k8) {
            f32x4 w4 = *(const f32x4*)&norm2_w[qtr * 32 + k8 * 4];
            f32x4 bb4 = *(const f32x4*)&norm2_b[qtr * 32 + k8 * 4];
            s4v o;
            #pragma unroll
            for (int u = 0; u < 4; ++u) o[u] = fb((v4[k8][u] - mu) * rs * w4[u] + bb4[u]);
            *(s4v*)&hb[t * SH + qtr * 32 + k8 * 4] = o;
        }
    }
    __syncthreads();

    // ---- preload a1 fragments; hb is then dead, gt aliases it ----
    short8 a1[2][4];
    #pragma unroll
    for (int mt = 0; mt < 2; ++mt)
        #pragma unroll
        for (int kk = 0; kk < 4; ++kk)
            a1[mt][kk] = *(const short8*)&hb[((wave * 2 + mt) * 16 + l16) * SH + kk * 32 + quad * 8];
    __syncthreads();   // all hb reads complete; gt (alias) may now be written
    short* gw = hb + wave * (32 * SG);   // per-wave 32 x SG gelu tile

    // ---- fc1 -> GELU -> fc2 (chunked over hidden), 2 m-tiles per wave ----
    {
        const short* w1 = wsb + WS_FC1;
        const short* w2 = wsb + WS_FC2;
        f32x4 acc[2][8];
        #pragma unroll
        for (int mt = 0; mt < 2; ++mt)
            #pragma unroll
            for (int n2 = 0; n2 < 8; ++n2) acc[mt][n2] = f32x4{0.f, 0.f, 0.f, 0.f};

        for (int h = 0; h < 16; ++h) {
            #pragma unroll
            for (int nt = 0; nt < 2; ++nt) {
                int n = h * 32 + nt * 16 + l16;
                short8 bfr[4];
                #pragma unroll
                for (int kk = 0; kk < 4; ++kk)
                    bfr[kk] = *(const short8*)&w1[n * Cc + kk * 32 + quad * 8];
                f32x4 c[2];
                c[0] = f32x4{0.f, 0.f, 0.f, 0.f};
                c[1] = f32x4{0.f, 0.f, 0.f, 0.f};
                #pragma unroll
                for (int kk = 0; kk < 4; ++kk)
                    #pragma unroll
                    for (int mt = 0; mt < 2; ++mt)
                        c[mt] = __builtin_amdgcn_mfma_f32_16x16x32_bf16(a1[mt][kk], bfr[kk], c[mt], 0, 0, 0);
                float bb = b1[n];
                #pragma unroll
                for (int mt = 0; mt < 2; ++mt)
                    #pragma unroll
                    for (int r = 0; r < 4; ++r) {
                        float g = fgelu(c[mt][r] + bb);
                        gw[(mt * 16 + quad * 4 + r) * SG + nt * 16 + l16] = fb(g);
                    }
            }
            // wave-private tile: lockstep write->read, no block barrier needed
            short8 a2[2];
            #pragma unroll
            for (int mt = 0; mt < 2; ++mt)
                a2[mt] = *(const short8*)&gw[(mt * 16 + l16) * SG + quad * 8];
            #pragma unroll
            for (int n2 = 0; n2 < 8; ++n2) {
                short8 bfr = *(const short8*)&w2[(n2 * 16 + l16) * HID + h * 32 + quad * 8];
                #pragma unroll
                for (int mt = 0; mt < 2; ++mt)
                    acc[mt][n2] = __builtin_amdgcn_mfma_f32_16x16x32_bf16(a2[mt], bfr, acc[mt][n2], 0, 0, 0);
            }
        }
        // epilogue: + bias + residual, in place
        #pragma unroll
        for (int mt = 0; mt < 2; ++mt)
            #pragma unroll
            for (int n2 = 0; n2 < 8; ++n2) {
                int cch = n2 * 16 + l16;
                float bb = b2[cch];
                #pragma unroll
                for (int r = 0; r < 4; ++r) {
                    int tok = (wave * 2 + mt) * 16 + quad * 4 + r;
                    size_t ad = base + (size_t)tok * Cc + cch;
                    xio[ad] = xio[ad] + acc[mt][n2][r] + bb;
                }
            }
    }
}

extern "C" void kernel_launch(void* const* d_in, const int* in_sizes, int n_in,
                              void* d_out, int out_size, void* d_ws, size_t ws_size,
                              hipStream_t stream) {
    const float* x         = (const float*)d_in[0];
    const float* x_norm1   = (const float*)d_in[1];
    const float* qkv_w     = (const float*)d_in[2];
    const float* qkv_b     = (const float*)d_in[3];
    const float* rel_bias  = (const float*)d_in[4];
    const float* proj_w    = (const float*)d_in[5];
    const float* proj_b    = (const float*)d_in[6];
    const float* norm2_w   = (const float*)d_in[7];
    const float* norm2_b   = (const float*)d_in[8];
    const float* fc1_w     = (const float*)d_in[9];
    const float* fc1_b     = (const float*)d_in[10];
    const float* fc2_w     = (const float*)d_in[11];
    const float* fc2_b     = (const float*)d_in[12];
    const float* attn_mask = (const float*)d_in[13];
    const int*   rel_index = (const int*)d_in[14];
    float* out = (float*)d_out;

    short* wsb   = (short*)d_ws;
    float* biasT = (float*)((char*)d_ws + WS_BIAS_BYTES);

    prep_kernel<<<768, 256, 0, stream>>>(qkv_w, proj_w, fc1_w, fc2_w,
                                         rel_bias, rel_index, wsb, biasT);

    attn_kernel<<<Bb * NW, 512, 0, stream>>>(x, x_norm1, qkv_b, proj_b,
                                             attn_mask, wsb, biasT, out);

    mlp_kernel<<<Bb * Hh * Ww / MTOK, 256, 0, stream>>>(norm2_w, norm2_b, fc1_b,
                                                        fc2_b, wsb, out);
}

// Round 8
// 659.694 us; speedup vs baseline: 2.0494x; 1.0595x over previous
//
#include <hip/hip_runtime.h>
#include <hip/hip_bf16.h>
#include <math.h>

typedef __hip_bfloat16 bf16;
typedef __attribute__((ext_vector_type(8))) short short8;
typedef __attribute__((ext_vector_type(4))) short s4v;
typedef __attribute__((ext_vector_type(4))) float f32x4;

#define Bb 64
#define Hh 56
#define Ww 56
#define Cc 128
#define WS 7
#define SHIFT 3
#define NH 4
#define HD 32
#define Nn 49
#define NW 64
#define HID 512

// ws layout (shorts): qkv_w @0 (49152), proj_w @49152 (16384), fc1_w @65536 (65536), fc2_w @131072 (65536)
// biasT (float) @ byte 393216: [4][49][49]
#define WS_QKV 0
#define WS_PROJ 49152
#define WS_FC1 65536
#define WS_FC2 131072
#define WS_BIAS_BYTES 393216

__device__ __forceinline__ short fb(float v) { return __builtin_bit_cast(short, __float2bfloat16(v)); }

// fast approximate reciprocal (v_rcp_f32, ~2^-22 rel err — fine for bf16 outputs)
__device__ __forceinline__ float frcp(float d) {
    float r;
    asm("v_rcp_f32 %0, %1" : "=v"(r) : "v"(d));
    return r;
}

// exp-based tanh GELU, division-free. |err| vs exact erf-GELU < 1e-3 (safe vs 0.031 budget).
__device__ __forceinline__ float fgelu(float x) {
    float z = x * x;
    float u = fmaf(z, 0.0713537069f, 1.5957691216f);   // (2y)/x
    float e = __expf(u * x);
    float r = frcp(e + 1.f);
    return fmaf(-x, r, x);
}

// ---------------- prep: weights fp32->bf16 into ws; gather rel-bias table ----------------
__global__ __launch_bounds__(256) void prep_kernel(
    const float* __restrict__ qkv_w, const float* __restrict__ proj_w,
    const float* __restrict__ fc1_w, const float* __restrict__ fc2_w,
    const float* __restrict__ rel_bias, const int* __restrict__ rel_index,
    short* __restrict__ wsb, float* __restrict__ biasT)
{
    int t = blockIdx.x * 256 + threadIdx.x;
    if (t < 49152)       wsb[t] = fb(qkv_w[t]);
    else if (t < 65536)  wsb[t] = fb(proj_w[t - 49152]);
    else if (t < 131072) wsb[t] = fb(fc1_w[t - 65536]);
    else if (t < 196608) wsb[t] = fb(fc2_w[t - 131072]);
    if (t < 4 * Nn * Nn) {
        int h = t / (Nn * Nn), r = t - h * (Nn * Nn);
        biasT[t] = rel_bias[rel_index[r] * NH + h];
    }
}

// ---------------- attention: one block per window, 8 waves (512 thr) ----------------
#define SW 136   // win/ao row stride (128 cols)
#define SQ 40    // qs/ks row stride (32 cols)
#define SV 72    // vT row stride (64 cols)
#define SP 72    // p row stride (64 cols)

// LDS budget: win 17408 B + qk (qs+ks) 40960 B + vT 18432 B = 76800 B -> 2 blocks/CU.
// pm (4*64*SP = 36864 B) ALIASES qk after the q/k register-preload barrier.
__global__ __launch_bounds__(512, 4) void attn_kernel(
    const float* __restrict__ x,          // (B,3136,128) shortcut
    const float* __restrict__ x_norm1,    // (B,3136,128)
    const float* __restrict__ qkv_b,      // (384)
    const float* __restrict__ proj_b,     // (128)
    const float* __restrict__ attn_mask,  // (64,49,49)
    const short* __restrict__ wsb,        // bf16 weights
    const float* __restrict__ biasT,      // (4,49,49)
    float* __restrict__ out)
{
    __shared__ short win[64 * SW];            // window tile; reused as attn_out
    __shared__ short qk[2 * NH * 64 * SQ];    // qs @0, ks @ NH*64*SQ; pm aliases @0
    __shared__ short vT[NH * HD * SV];

    const int blk = blockIdx.x;
    const int b   = blk >> 6;
    const int nw  = blk & 63;
    const int wh  = nw >> 3;
    const int wwi = nw & 7;
    const int tid  = threadIdx.x;
    const int wave = tid >> 6;
    const int lane = tid & 63;
    const int quad = lane >> 4;
    const int l16  = lane & 15;
    const int half = wave >> 2;    // 0/1 split used by score/PV phases
    const int mp   = wave >> 2;    // m-pair for QKV/proj phases
    const int wq   = wave & 3;     // n-slice for QKV/proj phases

    const int KS_OFF = NH * 64 * SQ;   // ks base inside qk

    // ---- gather shifted window, float4-vectorized (rows 49..63 zero) ----
    #pragma unroll
    for (int it = 0; it < 4; ++it) {
        int idx = it * 512 + tid;
        int t = idx >> 5, c4 = (idx & 31) * 4;
        f32x4 v = {0.f, 0.f, 0.f, 0.f};
        if (t < Nn) {
            int i = t / WS, j = t - i * WS;
            int hh = wh * WS + i + SHIFT; if (hh >= Hh) hh -= Hh;
            int wp = wwi * WS + j + SHIFT; if (wp >= Ww) wp -= Ww;
            v = *(const f32x4*)&x_norm1[((size_t)b * (Hh * Ww) + hh * Ww + wp) * Cc + c4];
        }
        s4v sv;
        #pragma unroll
        for (int u = 0; u < 4; ++u) sv[u] = fb(v[u]);
        *(s4v*)&win[t * SW + c4] = sv;
    }
    __syncthreads();

    // ---- QKV: wave (wq,mp): m-tiles {2mp,2mp+1}, n-tiles nt=j*4+wq, j=0..5 ----
    // Software-pipelined: j+1's weight fragments are issued before j's MFMAs.
    {
        short8 a1[2][4];
        #pragma unroll
        for (int mt = 0; mt < 2; ++mt)
            #pragma unroll
            for (int kk = 0; kk < 4; ++kk)
                a1[mt][kk] = *(const short8*)&win[((mp * 2 + mt) * 16 + l16) * SW + kk * 32 + quad * 8];
        const short* wqp = wsb + WS_QKV;
        float bias6[6];
        #pragma unroll
        for (int j = 0; j < 6; ++j) bias6[j] = qkv_b[(j * 4 + wq) * 16 + l16];
        const int dcol = (wq & 1) * 16 + l16;          // d for q/k/v targets
        short8 bfr[4];
        #pragma unroll
        for (int kk = 0; kk < 4; ++kk)
            bfr[kk] = *(const short8*)&wqp[(wq * 16 + l16) * Cc + kk * 32 + quad * 8];  // j=0
        #pragma unroll
        for (int j = 0; j < 6; ++j) {
            short8 nbf[4];
            if (j < 5) {
                const int nn = ((j + 1) * 4 + wq) * 16 + l16;
                #pragma unroll
                for (int kk = 0; kk < 4; ++kk)
                    nbf[kk] = *(const short8*)&wqp[nn * Cc + kk * 32 + quad * 8];
            }
            f32x4 c[2];
            c[0] = f32x4{0.f, 0.f, 0.f, 0.f};
            c[1] = f32x4{0.f, 0.f, 0.f, 0.f};
            #pragma unroll
            for (int kk = 0; kk < 4; ++kk)
                #pragma unroll
                for (int mt = 0; mt < 2; ++mt)
                    c[mt] = __builtin_amdgcn_mfma_f32_16x16x32_bf16(a1[mt][kk], bfr[kk], c[mt], 0, 0, 0);
            const int head = (wq >> 1) + 2 * (j & 1);  // = ((nt&7)>>1)
            const float bias = bias6[j];
            #pragma unroll
            for (int mt = 0; mt < 2; ++mt)
                #pragma unroll
                for (int r = 0; r < 4; ++r) {
                    int tok = (mp * 2 + mt) * 16 + quad * 4 + r;
                    float val = c[mt][r] + bias;
                    if (j < 2)      qk[head * 64 * SQ + tok * SQ + dcol] = fb(val * 0.17677669529663689f);
                    else if (j < 4) qk[KS_OFF + head * 64 * SQ + tok * SQ + dcol] = fb(val);
                    else            vT[head * HD * SV + dcol * SV + tok] = fb(val);
                }
            if (j < 5) {
                #pragma unroll
                for (int kk = 0; kk < 4; ++kk) bfr[kk] = nbf[kk];
            }
        }
    }
    __syncthreads();

    // ---- preload q/k fragments to registers, then free qs/ks for pm ----
    const int head = wave & 3;
    short8 bk[4], aq[2];
    #pragma unroll
    for (int nt = 0; nt < 4; ++nt)
        bk[nt] = *(const short8*)&qk[KS_OFF + head * 64 * SQ + (nt * 16 + l16) * SQ + quad * 8];
    #pragma unroll
    for (int i = 0; i < 2; ++i)
        aq[i] = *(const short8*)&qk[head * 64 * SQ + ((half * 2 + i) * 16 + l16) * SQ + quad * 8];
    __syncthreads();   // all q/k now in regs; pm may overwrite qk

    // ---- scores + softmax: wave (head,half) handles m-tiles {2*half, 2*half+1} ----
    {
        const float* bT = biasT + head * (Nn * Nn);
        const float* mk = attn_mask + nw * (Nn * Nn);
        #pragma unroll
        for (int i = 0; i < 2; ++i) {
            int mt = half * 2 + i;
            // prefetch bias+mask (independent of the MFMAs below -> overlaps L2 latency)
            float bm[4][4];
            #pragma unroll
            for (int r = 0; r < 4; ++r) {
                int row = mt * 16 + quad * 4 + r;
                bool rowv = row < Nn;
                int rb = row * Nn;
                #pragma unroll
                for (int nt = 0; nt < 4; ++nt) {
                    int col = nt * 16 + l16;
                    bm[r][nt] = (rowv && col < Nn) ? (bT[rb + col] + mk[rb + col]) : -1e30f;
                }
            }
            f32x4 sc[4];
            #pragma unroll
            for (int nt = 0; nt < 4; ++nt) {
                f32x4 z = {0.f, 0.f, 0.f, 0.f};
                sc[nt] = __builtin_amdgcn_mfma_f32_16x16x32_bf16(aq[i], bk[nt], z, 0, 0, 0);
            }
            #pragma unroll
            for (int r = 0; r < 4; ++r) {
                int row = mt * 16 + quad * 4 + r;
                float v[4];
                #pragma unroll
                for (int nt = 0; nt < 4; ++nt) v[nt] = sc[nt][r] + bm[r][nt];
                float mx = fmaxf(fmaxf(v[0], v[1]), fmaxf(v[2], v[3]));
                #pragma unroll
                for (int off = 1; off < 16; off <<= 1) mx = fmaxf(mx, __shfl_xor(mx, off, 64));
                float e[4]; float sum = 0.f;
                #pragma unroll
                for (int nt = 0; nt < 4; ++nt) { e[nt] = __expf(v[nt] - mx); sum += e[nt]; }
                #pragma unroll
                for (int off = 1; off < 16; off <<= 1) sum += __shfl_xor(sum, off, 64);
                float inv = frcp(sum);
                #pragma unroll
                for (int nt = 0; nt < 4; ++nt)
                    qk[head * 64 * SP + row * SP + nt * 16 + l16] = fb(e[nt] * inv);  // pm alias
            }
        }
    }
    // pm rows for this wave's m-tiles are wave-private; vT stable since QKV barrier.

    // ---- PV: O rows [half*32, half*32+32) x 32 per (head,half) ----
    {
        f32x4 o[2][2];
        #pragma unroll
        for (int i = 0; i < 2; ++i)
            #pragma unroll
            for (int nt = 0; nt < 2; ++nt) o[i][nt] = f32x4{0.f, 0.f, 0.f, 0.f};
        #pragma unroll
        for (int kstep = 0; kstep < 2; ++kstep) {
            short8 bv[2];
            #pragma unroll
            for (int nt = 0; nt < 2; ++nt)
                bv[nt] = *(const short8*)&vT[head * HD * SV + (nt * 16 + l16) * SV + kstep * 32 + quad * 8];
            #pragma unroll
            for (int i = 0; i < 2; ++i) {
                short8 ap = *(const short8*)&qk[head * 64 * SP + ((half * 2 + i) * 16 + l16) * SP + kstep * 32 + quad * 8];
                #pragma unroll
                for (int nt = 0; nt < 2; ++nt)
                    o[i][nt] = __builtin_amdgcn_mfma_f32_16x16x32_bf16(ap, bv[nt], o[i][nt], 0, 0, 0);
            }
        }
        #pragma unroll
        for (int i = 0; i < 2; ++i)
            #pragma unroll
            for (int nt = 0; nt < 2; ++nt)
                #pragma unroll
                for (int r = 0; r < 4; ++r) {
                    int tok = (half * 2 + i) * 16 + quad * 4 + r;
                    int cch = head * HD + nt * 16 + l16;
                    win[tok * SW + cch] = fb(o[i][nt][r]);
                }
    }
    __syncthreads();

    // ---- proj + residual + scatter: wave (wq,mp): m-tiles {2mp,2mp+1}, n-tiles {wq*2,wq*2+1} ----
    // Residual x values + both weight-fragment sets prefetched BEFORE the MFMA chain.
    {
        short8 a[2][4];
        #pragma unroll
        for (int mt = 0; mt < 2; ++mt)
            #pragma unroll
            for (int kk = 0; kk < 4; ++kk)
                a[mt][kk] = *(const short8*)&win[((mp * 2 + mt) * 16 + l16) * SW + kk * 32 + quad * 8];
        const short* wp_ = wsb + WS_PROJ;
        float pb2[2];
        #pragma unroll
        for (int j2 = 0; j2 < 2; ++j2) pb2[j2] = proj_b[(wq * 2 + j2) * 16 + l16];
        short8 wfr[2][4];
        #pragma unroll
        for (int j2 = 0; j2 < 2; ++j2) {
            const int n = (wq * 2 + j2) * 16 + l16;
            #pragma unroll
            for (int kk = 0; kk < 4; ++kk)
                wfr[j2][kk] = *(const short8*)&wp_[n * Cc + kk * 32 + quad * 8];
        }
        // residual prefetch (HBM latency hides under the MFMAs below)
        unsigned int off[2][4];
        float xv0[2][4], xv1[2][4];
        #pragma unroll
        for (int mt = 0; mt < 2; ++mt)
            #pragma unroll
            for (int r = 0; r < 4; ++r) {
                int tok = (mp * 2 + mt) * 16 + quad * 4 + r;
                if (tok < Nn) {
                    int i = tok / WS, j = tok - i * WS;
                    int hh = wh * WS + i + SHIFT; if (hh >= Hh) hh -= Hh;
                    int wpp = wwi * WS + j + SHIFT; if (wpp >= Ww) wpp -= Ww;
                    unsigned int o = (unsigned int)((b * (Hh * Ww) + hh * Ww + wpp) * Cc) + wq * 32 + l16;
                    off[mt][r] = o;
                    xv0[mt][r] = x[o];
                    xv1[mt][r] = x[o + 16];
                } else {
                    off[mt][r] = 0xFFFFFFFFu;
                    xv0[mt][r] = 0.f; xv1[mt][r] = 0.f;
                }
            }
        f32x4 c2[2][2];
        #pragma unroll
        for (int j2 = 0; j2 < 2; ++j2) {
            c2[j2][0] = f32x4{0.f, 0.f, 0.f, 0.f};
            c2[j2][1] = f32x4{0.f, 0.f, 0.f, 0.f};
        }
        #pragma unroll
        for (int kk = 0; kk < 4; ++kk)
            #pragma unroll
            for (int j2 = 0; j2 < 2; ++j2)
                #pragma unroll
                for (int mt = 0; mt < 2; ++mt)
                    c2[j2][mt] = __builtin_amdgcn_mfma_f32_16x16x32_bf16(a[mt][kk], wfr[j2][kk], c2[j2][mt], 0, 0, 0);
        #pragma unroll
        for (int mt = 0; mt < 2; ++mt)
            #pragma unroll
            for (int r = 0; r < 4; ++r)
                if (off[mt][r] != 0xFFFFFFFFu) {
                    out[off[mt][r]]      = xv0[mt][r] + c2[0][mt][r] + pb2[0];
                    out[off[mt][r] + 16] = xv1[mt][r] + c2[1][mt][r] + pb2[1];
                }
    }
}

// ---------------- MLP: 128 tokens/block, LN -> fc1 -> GELU -> fc2 -> residual ----------------
// gt ALIASES hb (hb dead after a1 preload + barrier). fc1 weight fragments are
// double-buffered (A/B alternating at half-h granularity) to hide L2 latency.
#define SH 136   // hb row stride
#define SG 40    // g tile row stride
#define MTOK 128 // tokens per block

__device__ __forceinline__ void fc1_step(
    const short* __restrict__ w1, const float* __restrict__ b1, short* __restrict__ gw,
    const short8 (&a1)[2][4], short8 (&cur)[4], short8 (&nxt)[4],
    const int h, const int nt, const int l16, const int quad)
{
    // prefetch next group's fragments (issues before this group's MFMAs retire)
    const int nh  = (nt == 0) ? h : ((h < 15) ? h + 1 : 15);
    const int n_nx = nh * 32 + (nt ^ 1) * 16 + l16;
    #pragma unroll
    for (int kk = 0; kk < 4; ++kk)
        nxt[kk] = *(const short8*)&w1[n_nx * Cc + kk * 32 + quad * 8];
    f32x4 c0 = {0.f, 0.f, 0.f, 0.f}, c1 = {0.f, 0.f, 0.f, 0.f};
    #pragma unroll
    for (int kk = 0; kk < 4; ++kk) {
        c0 = __builtin_amdgcn_mfma_f32_16x16x32_bf16(a1[0][kk], cur[kk], c0, 0, 0, 0);
        c1 = __builtin_amdgcn_mfma_f32_16x16x32_bf16(a1[1][kk], cur[kk], c1, 0, 0, 0);
    }
    const float bb = b1[h * 32 + nt * 16 + l16];
    #pragma unroll
    for (int r = 0; r < 4; ++r) {
        gw[(quad * 4 + r) * SG + nt * 16 + l16]        = fb(fgelu(c0[r] + bb));
        gw[(16 + quad * 4 + r) * SG + nt * 16 + l16]   = fb(fgelu(c1[r] + bb));
    }
}

__global__ __launch_bounds__(256, 3) void mlp_kernel(
    const float* __restrict__ norm2_w, const float* __restrict__ norm2_b,
    const float* __restrict__ fc1_b,   const float* __restrict__ fc2_b,
    const short* __restrict__ wsb,
    float* __restrict__ xio)
{
    __shared__ short hb[MTOK * SH];        // 34816 B; gt aliases the front of this
    __shared__ float b1[HID], b2[Cc];      // 2560 B

    const int tid  = threadIdx.x;
    const int wave = tid >> 6;
    const int lane = tid & 63;
    const int quad = lane >> 4;
    const int l16  = lane & 15;
    const size_t base = (size_t)blockIdx.x * MTOK * Cc;

    for (int i = tid; i < HID; i += 256) b1[i] = fc1_b[i];
    if (tid < Cc) b2[tid] = fc2_b[tid];

    // ---- LN: 4 threads per token, 2 tokens per thread ----
    #pragma unroll
    for (int rep = 0; rep < 2; ++rep) {
        int t = rep * 64 + (tid >> 2), qtr = tid & 3;
        const float* xr = xio + base + t * Cc + qtr * 32;
        f32x4 v4[8];
        float s1 = 0.f, s2 = 0.f;
        #pragma unroll
        for (int k8 = 0; k8 < 8; ++k8) {
            v4[k8] = *(const f32x4*)&xr[k8 * 4];
            #pragma unroll
            for (int u = 0; u < 4; ++u) { float v = v4[k8][u]; s1 += v; s2 += v * v; }
        }
        s1 += __shfl_xor(s1, 1, 64); s1 += __shfl_xor(s1, 2, 64);
        s2 += __shfl_xor(s2, 1, 64); s2 += __shfl_xor(s2, 2, 64);
        float mu = s1 * (1.f / Cc);
        float var = s2 * (1.f / Cc) - mu * mu;
        float rs = rsqrtf(var + 1e-5f);
        #pragma unroll
        for (int k8 = 0; k8 < 8; ++k8) {
            f32x4 w4 = *(const f32x4*)&norm2_w[qtr * 32 + k8 * 4];
            f32x4 bb4 = *(const f32x4*)&norm2_b[qtr * 32 + k8 * 4];
            s4v o;
            #pragma unroll
            for (int u = 0; u < 4; ++u) o[u] = fb((v4[k8][u] - mu) * rs * w4[u] + bb4[u]);
            *(s4v*)&hb[t * SH + qtr * 32 + k8 * 4] = o;
        }
    }
    __syncthreads();

    // ---- preload a1 fragments; hb is then dead, gt aliases it ----
    short8 a1[2][4];
    #pragma unroll
    for (int mt = 0; mt < 2; ++mt)
        #pragma unroll
        for (int kk = 0; kk < 4; ++kk)
            a1[mt][kk] = *(const short8*)&hb[((wave * 2 + mt) * 16 + l16) * SH + kk * 32 + quad * 8];
    __syncthreads();   // all hb reads complete; gt (alias) may now be written
    short* gw = hb + wave * (32 * SG);   // per-wave 32 x SG gelu tile

    // ---- fc1 -> GELU -> fc2 (chunked over hidden), pipelined ----
    {
        const short* w1 = wsb + WS_FC1;
        const short* w2 = wsb + WS_FC2;
        f32x4 acc[2][8];
        #pragma unroll
        for (int mt = 0; mt < 2; ++mt)
            #pragma unroll
            for (int n2 = 0; n2 < 8; ++n2) acc[mt][n2] = f32x4{0.f, 0.f, 0.f, 0.f};

        short8 nfA[4], nfB[4];
        #pragma unroll
        for (int kk = 0; kk < 4; ++kk)   // h=0, nt=0
            nfA[kk] = *(const short8*)&w1[l16 * Cc + kk * 32 + quad * 8];

        for (int h = 0; h < 16; ++h) {
            fc1_step(w1, b1, gw, a1, nfA, nfB, h, 0, l16, quad);
            fc1_step(w1, b1, gw, a1, nfB, nfA, h, 1, l16, quad);
            // fc2: weight loads issued in groups of 4 ahead of the dependent MFMAs
            short8 w2f[4];
            #pragma unroll
            for (int g = 0; g < 4; ++g)
                w2f[g] = *(const short8*)&w2[(g * 16 + l16) * HID + h * 32 + quad * 8];
            short8 a2[2];
            #pragma unroll
            for (int mt = 0; mt < 2; ++mt)
                a2[mt] = *(const short8*)&gw[(mt * 16 + l16) * SG + quad * 8];
            #pragma unroll
            for (int n2 = 0; n2 < 4; ++n2)
                #pragma unroll
                for (int mt = 0; mt < 2; ++mt)
                    acc[mt][n2] = __builtin_amdgcn_mfma_f32_16x16x32_bf16(a2[mt], w2f[n2], acc[mt][n2], 0, 0, 0);
            #pragma unroll
            for (int g = 0; g < 4; ++g)
                w2f[g] = *(const short8*)&w2[((g + 4) * 16 + l16) * HID + h * 32 + quad * 8];
            #pragma unroll
            for (int n2 = 4; n2 < 8; ++n2)
                #pragma unroll
                for (int mt = 0; mt < 2; ++mt)
                    acc[mt][n2] = __builtin_amdgcn_mfma_f32_16x16x32_bf16(a2[mt], w2f[n2 - 4], acc[mt][n2], 0, 0, 0);
        }
        // epilogue: + bias + residual, in place
        #pragma unroll
        for (int mt = 0; mt < 2; ++mt)
            #pragma unroll
            for (int n2 = 0; n2 < 8; ++n2) {
                int cch = n2 * 16 + l16;
                float bb = b2[cch];
                #pragma unroll
                for (int r = 0; r < 4; ++r) {
                    int tok = (wave * 2 + mt) * 16 + quad * 4 + r;
                    size_t ad = base + (size_t)tok * Cc + cch;
                    xio[ad] = xio[ad] + acc[mt][n2][r] + bb;
                }
            }
    }
}

extern "C" void kernel_launch(void* const* d_in, const int* in_sizes, int n_in,
                              void* d_out, int out_size, void* d_ws, size_t ws_size,
                              hipStream_t stream) {
    const float* x         = (const float*)d_in[0];
    const float* x_norm1   = (const float*)d_in[1];
    const float* qkv_w     = (const float*)d_in[2];
    const float* qkv_b     = (const float*)d_in[3];
    const float* rel_bias  = (const float*)d_in[4];
    const float* proj_w    = (const float*)d_in[5];
    const float* proj_b    = (const float*)d_in[6];
    const float* norm2_w   = (const float*)d_in[7];
    const float* norm2_b   = (const float*)d_in[8];
    const float* fc1_w     = (const float*)d_in[9];
    const float* fc1_b     = (const float*)d_in[10];
    const float* fc2_w     = (const float*)d_in[11];
    const float* fc2_b     = (const float*)d_in[12];
    const float* attn_mask = (const float*)d_in[13];
    const int*   rel_index = (const int*)d_in[14];
    float* out = (float*)d_out;

    short* wsb   = (short*)d_ws;
    float* biasT = (float*)((char*)d_ws + WS_BIAS_BYTES);

    prep_kernel<<<768, 256, 0, stream>>>(qkv_w, proj_w, fc1_w, fc2_w,
                                         rel_bias, rel_index, wsb, biasT);

    attn_kernel<<<Bb * NW, 512, 0, stream>>>(x, x_norm1, qkv_b, proj_b,
                                             attn_mask, wsb, biasT, out);

    mlp_kernel<<<Bb * Hh * Ww / MTOK, 256, 0, stream>>>(norm2_w, norm2_b, fc1_b,
                                                        fc2_b, wsb, out);
}